// Round 1
// baseline (356.603 us; speedup 1.0000x reference)
//
#include <hip/hip_runtime.h>
#include <math.h>

#define NN 10000
#define EE 320000
#define GG 64

__device__ __forceinline__ float leaky(float x) { return x >= 0.f ? x : 0.2f * x; }

// ---------------- setup kernels ----------------
__global__ __launch_bounds__(256) void zero_k(int* __restrict__ count,
                                              float* __restrict__ pooled,
                                              int* __restrict__ gcount) {
  int i = blockIdx.x * 256 + threadIdx.x;
  if (i < NN) count[i] = 0;
  if (i < GG * 128) pooled[i] = 0.f;
  if (i < GG) gcount[i] = 0;
}

__global__ __launch_bounds__(256) void hist_k(const int* __restrict__ ei,
                                              int* __restrict__ count) {
  int e = blockIdx.x * 256 + threadIdx.x;
  if (e < EE) atomicAdd(&count[ei[EE + e]], 1);
}

__global__ __launch_bounds__(1024) void scan_k(const int* __restrict__ count,
                                               int* __restrict__ rowstart,
                                               int* __restrict__ cursor) {
  __shared__ int part[1024];
  const int tid = threadIdx.x;
  const int PER = (NN + 1023) / 1024;  // 10
  int base = tid * PER;
  int local[PER];
  int s = 0;
#pragma unroll
  for (int i = 0; i < PER; i++) {
    int idx = base + i;
    int v = (idx < NN) ? count[idx] : 0;
    local[i] = s;
    s += v;
  }
  part[tid] = s;
  __syncthreads();
  for (int off = 1; off < 1024; off <<= 1) {
    int v = (tid >= off) ? part[tid - off] : 0;
    __syncthreads();
    part[tid] += v;
    __syncthreads();
  }
  int pre = (tid == 0) ? 0 : part[tid - 1];
#pragma unroll
  for (int i = 0; i < PER; i++) {
    int idx = base + i;
    if (idx < NN) { int v = pre + local[i]; rowstart[idx] = v; cursor[idx] = v; }
  }
  if (tid == 1023) rowstart[NN] = part[1023];
}

__global__ __launch_bounds__(256) void fill_k(const int* __restrict__ ei,
                                              int* __restrict__ cursor,
                                              int* __restrict__ esrc) {
  int e = blockIdx.x * 256 + threadIdx.x;
  if (e < EE) {
    int d = ei[EE + e];
    int pos = atomicAdd(&cursor[d], 1);
    esrc[pos] = ei[e];
  }
}

// ---------------- f32 tiled GEMM: C[M,Nc] = A[M,K] @ B[K,Nc] ----------------
// Requires Nc % 64 == 0, K % 16 == 0. M guarded.
__global__ __launch_bounds__(256) void gemm_k(const float* __restrict__ A,
                                              const float* __restrict__ B,
                                              float* __restrict__ C,
                                              int M, int K, int Nc) {
  const int BM = 64, BN = 64, BK = 16;
  __shared__ float As[BK][BM + 4];
  __shared__ float Bs[BK][BN + 4];
  const int tid = threadIdx.x;
  const int tr = tid >> 4;   // 0..15
  const int tc = tid & 15;   // 0..15
  const int brow = blockIdx.y * BM;
  const int bcol = blockIdx.x * BN;
  float acc[4][4] = {};
  for (int k0 = 0; k0 < K; k0 += BK) {
#pragma unroll
    for (int it = 0; it < (BM * BK) / 256; it++) {
      int i = tid + it * 256;
      int m = i >> 4, kk = i & 15;
      int gm = brow + m;
      As[kk][m] = (gm < M) ? A[(size_t)gm * K + k0 + kk] : 0.f;
    }
#pragma unroll
    for (int it = 0; it < (BK * BN) / 256; it++) {
      int i = tid + it * 256;
      int kk = i >> 6, nn = i & 63;
      Bs[kk][nn] = B[(size_t)(k0 + kk) * Nc + bcol + nn];
    }
    __syncthreads();
#pragma unroll
    for (int kk = 0; kk < BK; kk++) {
      float a[4], b[4];
#pragma unroll
      for (int i = 0; i < 4; i++) a[i] = As[kk][tr * 4 + i];
#pragma unroll
      for (int j = 0; j < 4; j++) b[j] = Bs[kk][tc * 4 + j];
#pragma unroll
      for (int i = 0; i < 4; i++)
#pragma unroll
        for (int j = 0; j < 4; j++) acc[i][j] = fmaf(a[i], b[j], acc[i][j]);
    }
    __syncthreads();
  }
#pragma unroll
  for (int i = 0; i < 4; i++) {
    int gm = brow + tr * 4 + i;
    if (gm < M) {
#pragma unroll
      for (int j = 0; j < 4; j++)
        C[(size_t)gm * Nc + bcol + tc * 4 + j] = acc[i][j];
    }
  }
}

// ---------------- alpha dots ----------------
__global__ __launch_bounds__(256) void alpha1_k(const float* __restrict__ h1,
                                                const float* __restrict__ a1s,
                                                const float* __restrict__ a1d,
                                                float* __restrict__ as1,
                                                float* __restrict__ ad1) {
  int n = blockIdx.x;
  int h = threadIdx.x >> 6;
  int lane = threadIdx.x & 63;
  const float* hp = h1 + (size_t)n * 512 + h * 128;
  const float* asp = a1s + h * 128;
  const float* adp = a1d + h * 128;
  float v0 = hp[lane], v1 = hp[lane + 64];
  float ss = v0 * asp[lane] + v1 * asp[lane + 64];
  float sd = v0 * adp[lane] + v1 * adp[lane + 64];
#pragma unroll
  for (int off = 32; off >= 1; off >>= 1) {
    ss += __shfl_xor(ss, off, 64);
    sd += __shfl_xor(sd, off, 64);
  }
  if (lane == 0) { as1[n * 4 + h] = ss; ad1[n * 4 + h] = sd; }
}

__global__ __launch_bounds__(64) void alpha2_k(const float* __restrict__ h2,
                                               const float* __restrict__ a2s,
                                               const float* __restrict__ a2d,
                                               float* __restrict__ as2,
                                               float* __restrict__ ad2) {
  int n = blockIdx.x;
  int lane = threadIdx.x;
  const float* hp = h2 + (size_t)n * 128;
  float v0 = hp[lane], v1 = hp[lane + 64];
  float ss = v0 * a2s[lane] + v1 * a2s[lane + 64];
  float sd = v0 * a2d[lane] + v1 * a2d[lane + 64];
#pragma unroll
  for (int off = 32; off >= 1; off >>= 1) {
    ss += __shfl_xor(ss, off, 64);
    sd += __shfl_xor(sd, off, 64);
  }
  if (lane == 0) { as2[n] = ss; ad2[n] = sd; }
}

// ---------------- layer-1 softmax + aggregation (4 heads, 512 ch) ----------------
__global__ __launch_bounds__(256) void agg1_k(const int* __restrict__ rowstart,
                                              const int* __restrict__ esrc,
                                              const float* __restrict__ as,
                                              const float* __restrict__ ad,
                                              const float* __restrict__ h1,
                                              const float* __restrict__ b1,
                                              float* __restrict__ out1) {
  const int n = blockIdx.x;
  const int tid = threadIdx.x;
  const int beg = rowstart[n];
  const int deg = rowstart[n + 1] - beg;
  const int tot = deg + 1;  // + self loop
  const float4* as4 = (const float4*)as;

  float4 adv = ((const float4*)ad)[n];

  __shared__ float4 red[256];
  __shared__ float4 s_w[128];
  __shared__ int s_src[128];

  // phase 1: per-head max
  float4 mx = make_float4(-1e30f, -1e30f, -1e30f, -1e30f);
  for (int i = tid; i < tot; i += 256) {
    int s = (i < deg) ? esrc[beg + i] : n;
    float4 av = as4[s];
    mx.x = fmaxf(mx.x, leaky(av.x + adv.x));
    mx.y = fmaxf(mx.y, leaky(av.y + adv.y));
    mx.z = fmaxf(mx.z, leaky(av.z + adv.z));
    mx.w = fmaxf(mx.w, leaky(av.w + adv.w));
  }
  red[tid] = mx;
  __syncthreads();
  for (int off = 128; off >= 1; off >>= 1) {
    if (tid < off) {
      float4 a = red[tid], b = red[tid + off];
      a.x = fmaxf(a.x, b.x); a.y = fmaxf(a.y, b.y);
      a.z = fmaxf(a.z, b.z); a.w = fmaxf(a.w, b.w);
      red[tid] = a;
    }
    __syncthreads();
  }
  float4 gmx = red[0];
  __syncthreads();

  // phase 2: per-head denom
  float4 sm = make_float4(0.f, 0.f, 0.f, 0.f);
  for (int i = tid; i < tot; i += 256) {
    int s = (i < deg) ? esrc[beg + i] : n;
    float4 av = as4[s];
    sm.x += expf(leaky(av.x + adv.x) - gmx.x);
    sm.y += expf(leaky(av.y + adv.y) - gmx.y);
    sm.z += expf(leaky(av.z + adv.z) - gmx.z);
    sm.w += expf(leaky(av.w + adv.w) - gmx.w);
  }
  red[tid] = sm;
  __syncthreads();
  for (int off = 128; off >= 1; off >>= 1) {
    if (tid < off) {
      float4 a = red[tid], b = red[tid + off];
      a.x += b.x; a.y += b.y; a.z += b.z; a.w += b.w;
      red[tid] = a;
    }
    __syncthreads();
  }
  float4 dn = red[0];
  float4 inv;
  inv.x = 1.f / (dn.x + 1e-16f); inv.y = 1.f / (dn.y + 1e-16f);
  inv.z = 1.f / (dn.z + 1e-16f); inv.w = 1.f / (dn.w + 1e-16f);
  __syncthreads();

  // phase 3: weighted aggregation, chunks of 128 edges in LDS
  float acc0 = 0.f, acc1 = 0.f;
  for (int base = 0; base < tot; base += 128) {
    int m = min(128, tot - base);
    for (int i = tid; i < m; i += 256) {
      int idx = base + i;
      int s = (idx < deg) ? esrc[beg + idx] : n;
      s_src[i] = s;
      float4 av = as4[s];
      float4 w;
      w.x = expf(leaky(av.x + adv.x) - gmx.x) * inv.x;
      w.y = expf(leaky(av.y + adv.y) - gmx.y) * inv.y;
      w.z = expf(leaky(av.z + adv.z) - gmx.z) * inv.z;
      w.w = expf(leaky(av.w + adv.w) - gmx.w) * inv.w;
      s_w[i] = w;
    }
    __syncthreads();
    for (int i = 0; i < m; i++) {
      int s = s_src[i];
      const float* hp = h1 + (size_t)s * 512;
      float4 w = s_w[i];
      float w0 = (tid < 128) ? w.x : w.y;   // head = tid>>7
      float w1 = (tid < 128) ? w.z : w.w;   // head = 2 + tid>>7
      acc0 = fmaf(w0, hp[tid], acc0);
      acc1 = fmaf(w1, hp[256 + tid], acc1);
    }
    __syncthreads();
  }
  float r0 = acc0 + b1[tid];
  float r1 = acc1 + b1[256 + tid];
  out1[(size_t)n * 512 + tid] = r0 > 0.f ? r0 : 0.f;
  out1[(size_t)n * 512 + 256 + tid] = r1 > 0.f ? r1 : 0.f;
}

// ---------------- layer-2 softmax + aggregation (1 head, 128 ch) ----------------
__global__ __launch_bounds__(128) void agg2_k(const int* __restrict__ rowstart,
                                              const int* __restrict__ esrc,
                                              const float* __restrict__ as,
                                              const float* __restrict__ ad,
                                              const float* __restrict__ h2,
                                              const float* __restrict__ b2,
                                              float* __restrict__ out2) {
  const int n = blockIdx.x;
  const int tid = threadIdx.x;
  const int beg = rowstart[n];
  const int deg = rowstart[n + 1] - beg;
  const int tot = deg + 1;
  float adv = ad[n];

  __shared__ float red[128];
  __shared__ float s_w[128];
  __shared__ int s_src[128];

  float mx = -1e30f;
  for (int i = tid; i < tot; i += 128) {
    int s = (i < deg) ? esrc[beg + i] : n;
    mx = fmaxf(mx, leaky(as[s] + adv));
  }
  red[tid] = mx;
  __syncthreads();
  for (int off = 64; off >= 1; off >>= 1) {
    if (tid < off) red[tid] = fmaxf(red[tid], red[tid + off]);
    __syncthreads();
  }
  float gmx = red[0];
  __syncthreads();

  float sm = 0.f;
  for (int i = tid; i < tot; i += 128) {
    int s = (i < deg) ? esrc[beg + i] : n;
    sm += expf(leaky(as[s] + adv) - gmx);
  }
  red[tid] = sm;
  __syncthreads();
  for (int off = 64; off >= 1; off >>= 1) {
    if (tid < off) red[tid] += red[tid + off];
    __syncthreads();
  }
  float invd = 1.f / (red[0] + 1e-16f);
  __syncthreads();

  float acc = 0.f;
  for (int base = 0; base < tot; base += 128) {
    int m = min(128, tot - base);
    if (tid < m) {
      int idx = base + tid;
      int s = (idx < deg) ? esrc[beg + idx] : n;
      s_src[tid] = s;
      s_w[tid] = expf(leaky(as[s] + adv) - gmx) * invd;
    }
    __syncthreads();
    for (int i = 0; i < m; i++)
      acc = fmaf(s_w[i], h2[(size_t)s_src[i] * 128 + tid], acc);
    __syncthreads();
  }
  float r = acc + b2[tid];
  out2[(size_t)n * 128 + tid] = r > 0.f ? r : 0.f;
}

// ---------------- pooling + FC ----------------
__global__ __launch_bounds__(128) void pool_k(const int* __restrict__ batch,
                                              const float* __restrict__ out2,
                                              float* __restrict__ pooled,
                                              int* __restrict__ gcount) {
  int n = blockIdx.x;
  int tid = threadIdx.x;
  int g = batch[n];
  atomicAdd(&pooled[g * 128 + tid], out2[(size_t)n * 128 + tid]);
  if (tid == 0) atomicAdd(&gcount[g], 1);
}

__global__ __launch_bounds__(64) void final_k(const float* __restrict__ pooled,
                                              const int* __restrict__ gcount,
                                              const float* __restrict__ fcw,
                                              const float* __restrict__ fcb,
                                              float* __restrict__ out) {
  int g = blockIdx.x, o = threadIdx.x;
  __shared__ float pg[128];
  int c = gcount[g];
  float icnt = 1.f / (float)(c > 0 ? c : 1);
  pg[o] = pooled[g * 128 + o] * icnt;
  pg[o + 64] = pooled[g * 128 + o + 64] * icnt;
  __syncthreads();
  float acc = fcb[o];
#pragma unroll 8
  for (int cc = 0; cc < 128; cc++) acc = fmaf(pg[cc], fcw[cc * 64 + o], acc);
  out[g * 64 + o] = acc;
}

// ---------------- launch ----------------
extern "C" void kernel_launch(void* const* d_in, const int* in_sizes, int n_in,
                              void* d_out, int out_size, void* d_ws, size_t ws_size,
                              hipStream_t stream) {
  const float* x   = (const float*)d_in[0];
  const int*   ei  = (const int*)d_in[1];
  const int*   bat = (const int*)d_in[2];
  const float* W1  = (const float*)d_in[3];
  const float* a1s = (const float*)d_in[4];
  const float* a1d = (const float*)d_in[5];
  const float* b1  = (const float*)d_in[6];
  const float* W2  = (const float*)d_in[7];
  const float* a2s = (const float*)d_in[8];
  const float* a2d = (const float*)d_in[9];
  const float* b2  = (const float*)d_in[10];
  const float* fcw = (const float*)d_in[11];
  const float* fcb = (const float*)d_in[12];
  float* out = (float*)d_out;

  char* ws = (char*)d_ws;
  size_t off = 0;
  auto alloc = [&](size_t bytes) -> void* {
    void* p = ws + off;
    off = (off + bytes + 255) & ~(size_t)255;
    return p;
  };

  int*   count    = (int*)alloc((size_t)NN * 4);
  int*   rowstart = (int*)alloc((size_t)(NN + 1) * 4);
  int*   cursor   = (int*)alloc((size_t)NN * 4);
  int*   esrc     = (int*)alloc((size_t)EE * 4);
  float* h1       = (float*)alloc((size_t)NN * 512 * 4);
  float* as1      = (float*)alloc((size_t)NN * 4 * 4);
  float* ad1      = (float*)alloc((size_t)NN * 4 * 4);
  float* out1     = (float*)alloc((size_t)NN * 512 * 4);
  float* h2       = (float*)alloc((size_t)NN * 128 * 4);
  float* as2      = (float*)alloc((size_t)NN * 4);
  float* ad2      = (float*)alloc((size_t)NN * 4);
  float* out2     = (float*)alloc((size_t)NN * 128 * 4);
  float* pooled   = (float*)alloc((size_t)GG * 128 * 4);
  int*   gcount   = (int*)alloc((size_t)GG * 4);
  (void)ws_size; (void)in_sizes; (void)n_in; (void)out_size;

  zero_k<<<(NN + 255) / 256, 256, 0, stream>>>(count, pooled, gcount);
  hist_k<<<(EE + 255) / 256, 256, 0, stream>>>(ei, count);
  scan_k<<<1, 1024, 0, stream>>>(count, rowstart, cursor);
  fill_k<<<(EE + 255) / 256, 256, 0, stream>>>(ei, cursor, esrc);

  gemm_k<<<dim3(512 / 64, (NN + 63) / 64), 256, 0, stream>>>(x, W1, h1, NN, 256, 512);
  alpha1_k<<<NN, 256, 0, stream>>>(h1, a1s, a1d, as1, ad1);
  agg1_k<<<NN, 256, 0, stream>>>(rowstart, esrc, as1, ad1, h1, b1, out1);

  gemm_k<<<dim3(128 / 64, (NN + 63) / 64), 256, 0, stream>>>(out1, W2, h2, NN, 512, 128);
  alpha2_k<<<NN, 64, 0, stream>>>(h2, a2s, a2d, as2, ad2);
  agg2_k<<<NN, 128, 0, stream>>>(rowstart, esrc, as2, ad2, h2, b2, out2);

  pool_k<<<NN, 128, 0, stream>>>(bat, out2, pooled, gcount);
  final_k<<<GG, 64, 0, stream>>>(pooled, gcount, fcw, fcb, out);
}

// Round 2
// 323.665 us; speedup vs baseline: 1.1018x; 1.1018x over previous
//
#include <hip/hip_runtime.h>
#include <math.h>

#define NN 10000
#define EE 320000
#define GG 64

__device__ __forceinline__ float leaky(float x) { return x >= 0.f ? x : 0.2f * x; }

__device__ __forceinline__ unsigned f2bf(float f) {
  unsigned u = __float_as_uint(f);
  return (u + 0x7fffu + ((u >> 16) & 1u)) >> 16;
}
__device__ __forceinline__ float bflo(unsigned v) { return __uint_as_float(v << 16); }
__device__ __forceinline__ float bfhi(unsigned v) { return __uint_as_float(v & 0xffff0000u); }
__device__ __forceinline__ float rdlanef(float v, int j) {
  return __uint_as_float(__builtin_amdgcn_readlane(__float_as_uint(v), j));
}

// ---------------- setup kernels ----------------
__global__ __launch_bounds__(256) void zero_k(int* __restrict__ count,
                                              float* __restrict__ pooled,
                                              int* __restrict__ gcount) {
  int i = blockIdx.x * 256 + threadIdx.x;
  if (i < NN) count[i] = 0;
  if (i < GG * 128) pooled[i] = 0.f;
  if (i < GG) gcount[i] = 0;
}

__global__ __launch_bounds__(256) void hist_k(const int* __restrict__ ei,
                                              int* __restrict__ count) {
  int e = blockIdx.x * 256 + threadIdx.x;
  if (e < EE) atomicAdd(&count[ei[EE + e]], 1);
}

__global__ __launch_bounds__(1024) void scan_k(const int* __restrict__ count,
                                               int* __restrict__ rowstart,
                                               int* __restrict__ cursor) {
  __shared__ int part[1024];
  const int tid = threadIdx.x;
  const int PER = (NN + 1023) / 1024;  // 10
  int base = tid * PER;
  int local[PER];
  int s = 0;
#pragma unroll
  for (int i = 0; i < PER; i++) {
    int idx = base + i;
    int v = (idx < NN) ? count[idx] : 0;
    local[i] = s;
    s += v;
  }
  part[tid] = s;
  __syncthreads();
  for (int off = 1; off < 1024; off <<= 1) {
    int v = (tid >= off) ? part[tid - off] : 0;
    __syncthreads();
    part[tid] += v;
    __syncthreads();
  }
  int pre = (tid == 0) ? 0 : part[tid - 1];
#pragma unroll
  for (int i = 0; i < PER; i++) {
    int idx = base + i;
    if (idx < NN) { int v = pre + local[i]; rowstart[idx] = v; cursor[idx] = v; }
  }
  if (tid == 1023) rowstart[NN] = part[1023];
}

__global__ __launch_bounds__(256) void fill_k(const int* __restrict__ ei,
                                              int* __restrict__ cursor,
                                              int* __restrict__ esrc) {
  int e = blockIdx.x * 256 + threadIdx.x;
  if (e < EE) {
    int d = ei[EE + e];
    int pos = atomicAdd(&cursor[d], 1);
    esrc[pos] = ei[e];
  }
}

// ---------------- f32 tiled GEMM: C[M,Nc] = A[M,K] @ B[K,Nc] ----------------
__global__ __launch_bounds__(256) void gemm_k(const float* __restrict__ A,
                                              const float* __restrict__ B,
                                              float* __restrict__ C,
                                              int M, int K, int Nc) {
  const int BM = 64, BN = 64, BK = 16;
  __shared__ float As[BK][BM + 4];
  __shared__ float Bs[BK][BN + 4];
  const int tid = threadIdx.x;
  const int tr = tid >> 4;   // 0..15
  const int tc = tid & 15;   // 0..15
  const int brow = blockIdx.y * BM;
  const int bcol = blockIdx.x * BN;
  float acc[4][4] = {};
  for (int k0 = 0; k0 < K; k0 += BK) {
#pragma unroll
    for (int it = 0; it < (BM * BK) / 256; it++) {
      int i = tid + it * 256;
      int m = i >> 4, kk = i & 15;
      int gm = brow + m;
      As[kk][m] = (gm < M) ? A[(size_t)gm * K + k0 + kk] : 0.f;
    }
#pragma unroll
    for (int it = 0; it < (BK * BN) / 256; it++) {
      int i = tid + it * 256;
      int kk = i >> 6, nn = i & 63;
      Bs[kk][nn] = B[(size_t)(k0 + kk) * Nc + bcol + nn];
    }
    __syncthreads();
#pragma unroll
    for (int kk = 0; kk < BK; kk++) {
      float a[4], b[4];
#pragma unroll
      for (int i = 0; i < 4; i++) a[i] = As[kk][tr * 4 + i];
#pragma unroll
      for (int j = 0; j < 4; j++) b[j] = Bs[kk][tc * 4 + j];
#pragma unroll
      for (int i = 0; i < 4; i++)
#pragma unroll
        for (int j = 0; j < 4; j++) acc[i][j] = fmaf(a[i], b[j], acc[i][j]);
    }
    __syncthreads();
  }
#pragma unroll
  for (int i = 0; i < 4; i++) {
    int gm = brow + tr * 4 + i;
    if (gm < M) {
#pragma unroll
      for (int j = 0; j < 4; j++)
        C[(size_t)gm * Nc + bcol + tc * 4 + j] = acc[i][j];
    }
  }
}

// ---------------- alpha dots ----------------
__global__ __launch_bounds__(256) void alpha1_k(const float* __restrict__ h1,
                                                const float* __restrict__ a1s,
                                                const float* __restrict__ a1d,
                                                float* __restrict__ as1,
                                                float* __restrict__ ad1) {
  int n = blockIdx.x;
  int h = threadIdx.x >> 6;
  int lane = threadIdx.x & 63;
  const float* hp = h1 + (size_t)n * 512 + h * 128;
  const float* asp = a1s + h * 128;
  const float* adp = a1d + h * 128;
  float v0 = hp[lane], v1 = hp[lane + 64];
  float ss = v0 * asp[lane] + v1 * asp[lane + 64];
  float sd = v0 * adp[lane] + v1 * adp[lane + 64];
#pragma unroll
  for (int off = 32; off >= 1; off >>= 1) {
    ss += __shfl_xor(ss, off, 64);
    sd += __shfl_xor(sd, off, 64);
  }
  if (lane == 0) { as1[n * 4 + h] = ss; ad1[n * 4 + h] = sd; }
}

__global__ __launch_bounds__(64) void alpha2_k(const float* __restrict__ h2,
                                               const float* __restrict__ a2s,
                                               const float* __restrict__ a2d,
                                               float* __restrict__ as2,
                                               float* __restrict__ ad2) {
  int n = blockIdx.x;
  int lane = threadIdx.x;
  const float* hp = h2 + (size_t)n * 128;
  float v0 = hp[lane], v1 = hp[lane + 64];
  float ss = v0 * a2s[lane] + v1 * a2s[lane + 64];
  float sd = v0 * a2d[lane] + v1 * a2d[lane + 64];
#pragma unroll
  for (int off = 32; off >= 1; off >>= 1) {
    ss += __shfl_xor(ss, off, 64);
    sd += __shfl_xor(sd, off, 64);
  }
  if (lane == 0) { as2[n] = ss; ad2[n] = sd; }
}

// ---------------- bf16 pack kernels ----------------
// h1p layout: per node, lane owns orig channels [lane*4..lane*4+4) and [256+lane*4..+4)
__global__ __launch_bounds__(256) void packh1_k(const float* __restrict__ h1,
                                                uint4* __restrict__ h1p) {
  int lane = threadIdx.x & 63;
  int n = blockIdx.x * 4 + (threadIdx.x >> 6);
  const float4* r = (const float4*)(h1 + (size_t)n * 512);
  float4 a = r[lane];
  float4 b = r[64 + lane];
  uint4 o;
  o.x = f2bf(a.x) | (f2bf(a.y) << 16);
  o.y = f2bf(a.z) | (f2bf(a.w) << 16);
  o.z = f2bf(b.x) | (f2bf(b.y) << 16);
  o.w = f2bf(b.z) | (f2bf(b.w) << 16);
  h1p[(size_t)n * 64 + lane] = o;
}

__global__ __launch_bounds__(256) void packh2_k(const float* __restrict__ h2,
                                                unsigned* __restrict__ h2b) {
  int lane = threadIdx.x & 63;
  int n = blockIdx.x * 4 + (threadIdx.x >> 6);
  float2 a = ((const float2*)(h2 + (size_t)n * 128))[lane];
  h2b[(size_t)n * 64 + lane] = f2bf(a.x) | (f2bf(a.y) << 16);
}

// ---------------- layer-1 softmax + aggregation: 1 wave per node ----------------
__global__ __launch_bounds__(256) void agg1_k(const int* __restrict__ rowstart,
                                              const int* __restrict__ esrc,
                                              const float* __restrict__ as,
                                              const float* __restrict__ ad,
                                              const uint4* __restrict__ h1p,
                                              const float* __restrict__ b1,
                                              float* __restrict__ out1) {
  const int lane = threadIdx.x & 63;
  const int n = blockIdx.x * 4 + (threadIdx.x >> 6);
  const int beg = rowstart[n];
  const int deg = rowstart[n + 1] - beg;
  const int tot = deg + 1;  // + self loop
  const float4* as4 = (const float4*)as;
  const float4 adv = ((const float4*)ad)[n];

  // first chunk cached in registers (covers deg<64, i.e. nearly all nodes)
  int s0 = n;
  float4 e0 = make_float4(-1e30f, -1e30f, -1e30f, -1e30f);
  if (lane < tot) {
    if (lane < deg) s0 = esrc[beg + lane];
    float4 av = as4[s0];
    e0.x = leaky(av.x + adv.x); e0.y = leaky(av.y + adv.y);
    e0.z = leaky(av.z + adv.z); e0.w = leaky(av.w + adv.w);
  }
  float4 mx = e0;
  for (int i = lane + 64; i < tot; i += 64) {
    int s = (i < deg) ? esrc[beg + i] : n;
    float4 av = as4[s];
    mx.x = fmaxf(mx.x, leaky(av.x + adv.x));
    mx.y = fmaxf(mx.y, leaky(av.y + adv.y));
    mx.z = fmaxf(mx.z, leaky(av.z + adv.z));
    mx.w = fmaxf(mx.w, leaky(av.w + adv.w));
  }
#pragma unroll
  for (int off = 32; off >= 1; off >>= 1) {
    mx.x = fmaxf(mx.x, __shfl_xor(mx.x, off, 64));
    mx.y = fmaxf(mx.y, __shfl_xor(mx.y, off, 64));
    mx.z = fmaxf(mx.z, __shfl_xor(mx.z, off, 64));
    mx.w = fmaxf(mx.w, __shfl_xor(mx.w, off, 64));
  }
  // denom (e0 = -1e30 on inactive lanes -> exp -> 0)
  float4 sm;
  sm.x = __expf(e0.x - mx.x); sm.y = __expf(e0.y - mx.y);
  sm.z = __expf(e0.z - mx.z); sm.w = __expf(e0.w - mx.w);
  for (int i = lane + 64; i < tot; i += 64) {
    int s = (i < deg) ? esrc[beg + i] : n;
    float4 av = as4[s];
    sm.x += __expf(leaky(av.x + adv.x) - mx.x);
    sm.y += __expf(leaky(av.y + adv.y) - mx.y);
    sm.z += __expf(leaky(av.z + adv.z) - mx.z);
    sm.w += __expf(leaky(av.w + adv.w) - mx.w);
  }
#pragma unroll
  for (int off = 32; off >= 1; off >>= 1) {
    sm.x += __shfl_xor(sm.x, off, 64);
    sm.y += __shfl_xor(sm.y, off, 64);
    sm.z += __shfl_xor(sm.z, off, 64);
    sm.w += __shfl_xor(sm.w, off, 64);
  }
  float4 inv;
  inv.x = 1.f / (sm.x + 1e-16f); inv.y = 1.f / (sm.y + 1e-16f);
  inv.z = 1.f / (sm.z + 1e-16f); inv.w = 1.f / (sm.w + 1e-16f);

  float4 acc0 = make_float4(0.f, 0.f, 0.f, 0.f);
  float4 acc1 = make_float4(0.f, 0.f, 0.f, 0.f);
  for (int base = 0; base < tot; base += 64) {
    int sl;
    float4 wl;
    if (base == 0) {
      sl = s0;
      wl.x = __expf(e0.x - mx.x) * inv.x;
      wl.y = __expf(e0.y - mx.y) * inv.y;
      wl.z = __expf(e0.z - mx.z) * inv.z;
      wl.w = __expf(e0.w - mx.w) * inv.w;
    } else {
      int i = base + lane;
      sl = n;
      wl = make_float4(0.f, 0.f, 0.f, 0.f);
      if (i < tot) {
        if (i < deg) sl = esrc[beg + i];
        float4 av = as4[sl];
        wl.x = __expf(leaky(av.x + adv.x) - mx.x) * inv.x;
        wl.y = __expf(leaky(av.y + adv.y) - mx.y) * inv.y;
        wl.z = __expf(leaky(av.z + adv.z) - mx.z) * inv.z;
        wl.w = __expf(leaky(av.w + adv.w) - mx.w) * inv.w;
      }
    }
    int m = min(64, tot - base);
    for (int j = 0; j < m; ++j) {
      int s = __builtin_amdgcn_readlane(sl, j);
      float wx = rdlanef(wl.x, j);
      float wy = rdlanef(wl.y, j);
      float wz = rdlanef(wl.z, j);
      float ww = rdlanef(wl.w, j);
      float wA = (lane < 32) ? wx : wy;  // heads 0/1
      float wB = (lane < 32) ? wz : ww;  // heads 2/3
      uint4 hv = h1p[(size_t)s * 64 + lane];
      acc0.x = fmaf(wA, bflo(hv.x), acc0.x);
      acc0.y = fmaf(wA, bfhi(hv.x), acc0.y);
      acc0.z = fmaf(wA, bflo(hv.y), acc0.z);
      acc0.w = fmaf(wA, bfhi(hv.y), acc0.w);
      acc1.x = fmaf(wB, bflo(hv.z), acc1.x);
      acc1.y = fmaf(wB, bfhi(hv.z), acc1.y);
      acc1.z = fmaf(wB, bflo(hv.w), acc1.z);
      acc1.w = fmaf(wB, bfhi(hv.w), acc1.w);
    }
  }
  float4 bA = ((const float4*)b1)[lane];
  float4 bB = ((const float4*)b1)[64 + lane];
  float4 r0, r1;
  r0.x = fmaxf(acc0.x + bA.x, 0.f); r0.y = fmaxf(acc0.y + bA.y, 0.f);
  r0.z = fmaxf(acc0.z + bA.z, 0.f); r0.w = fmaxf(acc0.w + bA.w, 0.f);
  r1.x = fmaxf(acc1.x + bB.x, 0.f); r1.y = fmaxf(acc1.y + bB.y, 0.f);
  r1.z = fmaxf(acc1.z + bB.z, 0.f); r1.w = fmaxf(acc1.w + bB.w, 0.f);
  ((float4*)(out1 + (size_t)n * 512))[lane] = r0;
  ((float4*)(out1 + (size_t)n * 512 + 256))[lane] = r1;
}

// ---------------- layer-2 softmax + aggregation: 1 wave per node ----------------
__global__ __launch_bounds__(256) void agg2_k(const int* __restrict__ rowstart,
                                              const int* __restrict__ esrc,
                                              const float* __restrict__ as,
                                              const float* __restrict__ ad,
                                              const unsigned* __restrict__ h2b,
                                              const float* __restrict__ b2,
                                              float* __restrict__ out2) {
  const int lane = threadIdx.x & 63;
  const int n = blockIdx.x * 4 + (threadIdx.x >> 6);
  const int beg = rowstart[n];
  const int deg = rowstart[n + 1] - beg;
  const int tot = deg + 1;
  const float adv = ad[n];

  int s0 = n;
  float e0 = -1e30f;
  if (lane < tot) {
    if (lane < deg) s0 = esrc[beg + lane];
    e0 = leaky(as[s0] + adv);
  }
  float mx = e0;
  for (int i = lane + 64; i < tot; i += 64) {
    int s = (i < deg) ? esrc[beg + i] : n;
    mx = fmaxf(mx, leaky(as[s] + adv));
  }
#pragma unroll
  for (int off = 32; off >= 1; off >>= 1) mx = fmaxf(mx, __shfl_xor(mx, off, 64));
  float sm = __expf(e0 - mx);
  for (int i = lane + 64; i < tot; i += 64) {
    int s = (i < deg) ? esrc[beg + i] : n;
    sm += __expf(leaky(as[s] + adv) - mx);
  }
#pragma unroll
  for (int off = 32; off >= 1; off >>= 1) sm += __shfl_xor(sm, off, 64);
  float inv = 1.f / (sm + 1e-16f);

  float2 acc = make_float2(0.f, 0.f);
  for (int base = 0; base < tot; base += 64) {
    int sl;
    float wl;
    if (base == 0) {
      sl = s0;
      wl = __expf(e0 - mx) * inv;
    } else {
      int i = base + lane;
      sl = n; wl = 0.f;
      if (i < tot) {
        if (i < deg) sl = esrc[beg + i];
        wl = __expf(leaky(as[sl] + adv) - mx) * inv;
      }
    }
    int m = min(64, tot - base);
    for (int j = 0; j < m; ++j) {
      int s = __builtin_amdgcn_readlane(sl, j);
      float w = rdlanef(wl, j);
      unsigned hv = h2b[(size_t)s * 64 + lane];
      acc.x = fmaf(w, bflo(hv), acc.x);
      acc.y = fmaf(w, bfhi(hv), acc.y);
    }
  }
  float2 bb = ((const float2*)b2)[lane];
  float2 r;
  r.x = fmaxf(acc.x + bb.x, 0.f);
  r.y = fmaxf(acc.y + bb.y, 0.f);
  ((float2*)(out2 + (size_t)n * 128))[lane] = r;
}

// ---------------- pooling + FC ----------------
__global__ __launch_bounds__(128) void pool_k(const int* __restrict__ batch,
                                              const float* __restrict__ out2,
                                              float* __restrict__ pooled,
                                              int* __restrict__ gcount) {
  int n = blockIdx.x;
  int tid = threadIdx.x;
  int g = batch[n];
  atomicAdd(&pooled[g * 128 + tid], out2[(size_t)n * 128 + tid]);
  if (tid == 0) atomicAdd(&gcount[g], 1);
}

__global__ __launch_bounds__(64) void final_k(const float* __restrict__ pooled,
                                              const int* __restrict__ gcount,
                                              const float* __restrict__ fcw,
                                              const float* __restrict__ fcb,
                                              float* __restrict__ out) {
  int g = blockIdx.x, o = threadIdx.x;
  __shared__ float pg[128];
  int c = gcount[g];
  float icnt = 1.f / (float)(c > 0 ? c : 1);
  pg[o] = pooled[g * 128 + o] * icnt;
  pg[o + 64] = pooled[g * 128 + o + 64] * icnt;
  __syncthreads();
  float acc = fcb[o];
#pragma unroll 8
  for (int cc = 0; cc < 128; cc++) acc = fmaf(pg[cc], fcw[cc * 64 + o], acc);
  out[g * 64 + o] = acc;
}

// ---------------- launch ----------------
extern "C" void kernel_launch(void* const* d_in, const int* in_sizes, int n_in,
                              void* d_out, int out_size, void* d_ws, size_t ws_size,
                              hipStream_t stream) {
  const float* x   = (const float*)d_in[0];
  const int*   ei  = (const int*)d_in[1];
  const int*   bat = (const int*)d_in[2];
  const float* W1  = (const float*)d_in[3];
  const float* a1s = (const float*)d_in[4];
  const float* a1d = (const float*)d_in[5];
  const float* b1  = (const float*)d_in[6];
  const float* W2  = (const float*)d_in[7];
  const float* a2s = (const float*)d_in[8];
  const float* a2d = (const float*)d_in[9];
  const float* b2  = (const float*)d_in[10];
  const float* fcw = (const float*)d_in[11];
  const float* fcb = (const float*)d_in[12];
  float* out = (float*)d_out;

  char* ws = (char*)d_ws;
  size_t off = 0;
  auto alloc = [&](size_t bytes) -> void* {
    void* p = ws + off;
    off = (off + bytes + 255) & ~(size_t)255;
    return p;
  };

  int*   count    = (int*)alloc((size_t)NN * 4);
  int*   rowstart = (int*)alloc((size_t)(NN + 1) * 4);
  int*   cursor   = (int*)alloc((size_t)NN * 4);
  int*   esrc     = (int*)alloc((size_t)EE * 4);
  float* h1       = (float*)alloc((size_t)NN * 512 * 4);
  float* as1      = (float*)alloc((size_t)NN * 4 * 4);
  float* ad1      = (float*)alloc((size_t)NN * 4 * 4);
  float* out1     = (float*)alloc((size_t)NN * 512 * 4);
  float* h2       = (float*)alloc((size_t)NN * 128 * 4);
  float* as2      = (float*)alloc((size_t)NN * 4);
  float* ad2      = (float*)alloc((size_t)NN * 4);
  float* out2     = (float*)alloc((size_t)NN * 128 * 4);
  float* pooled   = (float*)alloc((size_t)GG * 128 * 4);
  int*   gcount   = (int*)alloc((size_t)GG * 4);
  uint4* h1p      = (uint4*)alloc((size_t)NN * 512 * 2);
  unsigned* h2b   = (unsigned*)alloc((size_t)NN * 128 * 2);
  (void)ws_size; (void)in_sizes; (void)n_in; (void)out_size;

  zero_k<<<(NN + 255) / 256, 256, 0, stream>>>(count, pooled, gcount);
  hist_k<<<(EE + 255) / 256, 256, 0, stream>>>(ei, count);
  scan_k<<<1, 1024, 0, stream>>>(count, rowstart, cursor);
  fill_k<<<(EE + 255) / 256, 256, 0, stream>>>(ei, cursor, esrc);

  gemm_k<<<dim3(512 / 64, (NN + 63) / 64), 256, 0, stream>>>(x, W1, h1, NN, 256, 512);
  alpha1_k<<<NN, 256, 0, stream>>>(h1, a1s, a1d, as1, ad1);
  packh1_k<<<NN / 4, 256, 0, stream>>>(h1, h1p);
  agg1_k<<<NN / 4, 256, 0, stream>>>(rowstart, esrc, as1, ad1, h1p, b1, out1);

  gemm_k<<<dim3(128 / 64, (NN + 63) / 64), 256, 0, stream>>>(out1, W2, h2, NN, 512, 128);
  alpha2_k<<<NN, 64, 0, stream>>>(h2, a2s, a2d, as2, ad2);
  packh2_k<<<NN / 4, 256, 0, stream>>>(h2, h2b);
  agg2_k<<<NN / 4, 256, 0, stream>>>(rowstart, esrc, as2, ad2, h2b, b2, out2);

  pool_k<<<NN, 128, 0, stream>>>(bat, out2, pooled, gcount);
  final_k<<<GG, 64, 0, stream>>>(pooled, gcount, fcw, fcb, out);
}

// Round 3
// 272.303 us; speedup vs baseline: 1.3096x; 1.1886x over previous
//
#include <hip/hip_runtime.h>
#include <math.h>

#define NN 10000
#define EE 320000
#define GG 64

__device__ __forceinline__ float leaky(float x) { return x >= 0.f ? x : 0.2f * x; }

__device__ __forceinline__ unsigned f2bf(float f) {
  unsigned u = __float_as_uint(f);
  return (u + 0x7fffu + ((u >> 16) & 1u)) >> 16;
}
__device__ __forceinline__ float bflo(unsigned v) { return __uint_as_float(v << 16); }
__device__ __forceinline__ float bfhi(unsigned v) { return __uint_as_float(v & 0xffff0000u); }
__device__ __forceinline__ float rdlanef(float v, int j) {
  return __uint_as_float(__builtin_amdgcn_readlane(__float_as_uint(v), j));
}

// ---------------- setup kernels ----------------
__global__ __launch_bounds__(256) void zero_k(int* __restrict__ count) {
  int i = blockIdx.x * 256 + threadIdx.x;
  if (i < NN) count[i] = 0;
}

__global__ __launch_bounds__(256) void hist_k(const int* __restrict__ ei,
                                              int* __restrict__ count) {
  int e = blockIdx.x * 256 + threadIdx.x;
  if (e < EE) atomicAdd(&count[ei[EE + e]], 1);
}

__global__ __launch_bounds__(1024) void scan_k(const int* __restrict__ count,
                                               int* __restrict__ rowstart,
                                               int* __restrict__ cursor) {
  __shared__ int part[1024];
  const int tid = threadIdx.x;
  const int PER = (NN + 1023) / 1024;  // 10
  int base = tid * PER;
  int local[PER];
  int s = 0;
#pragma unroll
  for (int i = 0; i < PER; i++) {
    int idx = base + i;
    int v = (idx < NN) ? count[idx] : 0;
    local[i] = s;
    s += v;
  }
  part[tid] = s;
  __syncthreads();
  for (int off = 1; off < 1024; off <<= 1) {
    int v = (tid >= off) ? part[tid - off] : 0;
    __syncthreads();
    part[tid] += v;
    __syncthreads();
  }
  int pre = (tid == 0) ? 0 : part[tid - 1];
#pragma unroll
  for (int i = 0; i < PER; i++) {
    int idx = base + i;
    if (idx < NN) { int v = pre + local[i]; rowstart[idx] = v; cursor[idx] = v; }
  }
  if (tid == 1023) rowstart[NN] = part[1023];
}

__global__ __launch_bounds__(256) void fill_k(const int* __restrict__ ei,
                                              int* __restrict__ cursor,
                                              int* __restrict__ esrc) {
  int e = blockIdx.x * 256 + threadIdx.x;
  if (e < EE) {
    int d = ei[EE + e];
    int pos = atomicAdd(&cursor[d], 1);
    esrc[pos] = ei[e];
  }
}

// graph segment boundaries from sorted batch
__global__ __launch_bounds__(256) void gstart_k(const int* __restrict__ batch,
                                                int* __restrict__ gstart) {
  int i = blockIdx.x * 256 + threadIdx.x;
  if (i >= NN) return;
  int b = batch[i];
  int prev = (i == 0) ? -1 : batch[i - 1];
  for (int g = prev + 1; g <= b; g++) gstart[g] = i;
  if (i == NN - 1)
    for (int g = b + 1; g <= GG; g++) gstart[g] = NN;
}

// ---------------- f32 tiled GEMM: C[M,Nc] = A[M,K] @ B[K,Nc] ----------------
__global__ __launch_bounds__(256) void gemm_k(const float* __restrict__ A,
                                              const float* __restrict__ B,
                                              float* __restrict__ C,
                                              int M, int K, int Nc) {
  const int BM = 64, BN = 64, BK = 16;
  __shared__ float As[BK][BM + 4];
  __shared__ float Bs[BK][BN + 4];
  const int tid = threadIdx.x;
  const int tr = tid >> 4;   // 0..15
  const int tc = tid & 15;   // 0..15
  const int brow = blockIdx.y * BM;
  const int bcol = blockIdx.x * BN;
  float acc[4][4] = {};
  for (int k0 = 0; k0 < K; k0 += BK) {
#pragma unroll
    for (int it = 0; it < (BM * BK) / 256; it++) {
      int i = tid + it * 256;
      int m = i >> 4, kk = i & 15;
      int gm = brow + m;
      As[kk][m] = (gm < M) ? A[(size_t)gm * K + k0 + kk] : 0.f;
    }
#pragma unroll
    for (int it = 0; it < (BK * BN) / 256; it++) {
      int i = tid + it * 256;
      int kk = i >> 6, nn = i & 63;
      Bs[kk][nn] = B[(size_t)(k0 + kk) * Nc + bcol + nn];
    }
    __syncthreads();
#pragma unroll
    for (int kk = 0; kk < BK; kk++) {
      float a[4], b[4];
#pragma unroll
      for (int i = 0; i < 4; i++) a[i] = As[kk][tr * 4 + i];
#pragma unroll
      for (int j = 0; j < 4; j++) b[j] = Bs[kk][tc * 4 + j];
#pragma unroll
      for (int i = 0; i < 4; i++)
#pragma unroll
        for (int j = 0; j < 4; j++) acc[i][j] = fmaf(a[i], b[j], acc[i][j]);
    }
    __syncthreads();
  }
#pragma unroll
  for (int i = 0; i < 4; i++) {
    int gm = brow + tr * 4 + i;
    if (gm < M) {
#pragma unroll
      for (int j = 0; j < 4; j++)
        C[(size_t)gm * Nc + bcol + tc * 4 + j] = acc[i][j];
    }
  }
}

// ---------------- alpha dots ----------------
__global__ __launch_bounds__(256) void alpha1_k(const float* __restrict__ h1,
                                                const float* __restrict__ a1s,
                                                const float* __restrict__ a1d,
                                                float* __restrict__ as1,
                                                float* __restrict__ ad1) {
  int n = blockIdx.x;
  int h = threadIdx.x >> 6;
  int lane = threadIdx.x & 63;
  const float* hp = h1 + (size_t)n * 512 + h * 128;
  const float* asp = a1s + h * 128;
  const float* adp = a1d + h * 128;
  float v0 = hp[lane], v1 = hp[lane + 64];
  float ss = v0 * asp[lane] + v1 * asp[lane + 64];
  float sd = v0 * adp[lane] + v1 * adp[lane + 64];
#pragma unroll
  for (int off = 32; off >= 1; off >>= 1) {
    ss += __shfl_xor(ss, off, 64);
    sd += __shfl_xor(sd, off, 64);
  }
  if (lane == 0) { as1[n * 4 + h] = ss; ad1[n * 4 + h] = sd; }
}

__global__ __launch_bounds__(64) void alpha2_k(const float* __restrict__ h2,
                                               const float* __restrict__ a2s,
                                               const float* __restrict__ a2d,
                                               float* __restrict__ as2,
                                               float* __restrict__ ad2) {
  int n = blockIdx.x;
  int lane = threadIdx.x;
  const float* hp = h2 + (size_t)n * 128;
  float v0 = hp[lane], v1 = hp[lane + 64];
  float ss = v0 * a2s[lane] + v1 * a2s[lane + 64];
  float sd = v0 * a2d[lane] + v1 * a2d[lane + 64];
#pragma unroll
  for (int off = 32; off >= 1; off >>= 1) {
    ss += __shfl_xor(ss, off, 64);
    sd += __shfl_xor(sd, off, 64);
  }
  if (lane == 0) { as2[n] = ss; ad2[n] = sd; }
}

// ---------------- bf16 pack kernels ----------------
__global__ __launch_bounds__(256) void packh1_k(const float* __restrict__ h1,
                                                uint4* __restrict__ h1p) {
  int lane = threadIdx.x & 63;
  int n = blockIdx.x * 4 + (threadIdx.x >> 6);
  const float4* r = (const float4*)(h1 + (size_t)n * 512);
  float4 a = r[lane];
  float4 b = r[64 + lane];
  uint4 o;
  o.x = f2bf(a.x) | (f2bf(a.y) << 16);
  o.y = f2bf(a.z) | (f2bf(a.w) << 16);
  o.z = f2bf(b.x) | (f2bf(b.y) << 16);
  o.w = f2bf(b.z) | (f2bf(b.w) << 16);
  h1p[(size_t)n * 64 + lane] = o;
}

__global__ __launch_bounds__(256) void packh2_k(const float* __restrict__ h2,
                                                unsigned* __restrict__ h2b) {
  int lane = threadIdx.x & 63;
  int n = blockIdx.x * 4 + (threadIdx.x >> 6);
  float2 a = ((const float2*)(h2 + (size_t)n * 128))[lane];
  h2b[(size_t)n * 64 + lane] = f2bf(a.x) | (f2bf(a.y) << 16);
}

// ---------------- layer-1 softmax + aggregation: 1 wave per node ----------------
__global__ __launch_bounds__(256) void agg1_k(const int* __restrict__ rowstart,
                                              const int* __restrict__ esrc,
                                              const float* __restrict__ as,
                                              const float* __restrict__ ad,
                                              const uint4* __restrict__ h1p,
                                              const float* __restrict__ b1,
                                              float* __restrict__ out1) {
  const int lane = threadIdx.x & 63;
  const int n = blockIdx.x * 4 + (threadIdx.x >> 6);
  const int beg = rowstart[n];
  const int deg = rowstart[n + 1] - beg;
  const int tot = deg + 1;  // + self loop
  const float4* as4 = (const float4*)as;
  const float4 adv = ((const float4*)ad)[n];

  int s0 = n;
  float4 e0 = make_float4(-1e30f, -1e30f, -1e30f, -1e30f);
  if (lane < tot) {
    if (lane < deg) s0 = esrc[beg + lane];
    float4 av = as4[s0];
    e0.x = leaky(av.x + adv.x); e0.y = leaky(av.y + adv.y);
    e0.z = leaky(av.z + adv.z); e0.w = leaky(av.w + adv.w);
  }
  float4 mx = e0;
  for (int i = lane + 64; i < tot; i += 64) {
    int s = (i < deg) ? esrc[beg + i] : n;
    float4 av = as4[s];
    mx.x = fmaxf(mx.x, leaky(av.x + adv.x));
    mx.y = fmaxf(mx.y, leaky(av.y + adv.y));
    mx.z = fmaxf(mx.z, leaky(av.z + adv.z));
    mx.w = fmaxf(mx.w, leaky(av.w + adv.w));
  }
#pragma unroll
  for (int off = 32; off >= 1; off >>= 1) {
    mx.x = fmaxf(mx.x, __shfl_xor(mx.x, off, 64));
    mx.y = fmaxf(mx.y, __shfl_xor(mx.y, off, 64));
    mx.z = fmaxf(mx.z, __shfl_xor(mx.z, off, 64));
    mx.w = fmaxf(mx.w, __shfl_xor(mx.w, off, 64));
  }
  float4 sm;
  sm.x = __expf(e0.x - mx.x); sm.y = __expf(e0.y - mx.y);
  sm.z = __expf(e0.z - mx.z); sm.w = __expf(e0.w - mx.w);
  for (int i = lane + 64; i < tot; i += 64) {
    int s = (i < deg) ? esrc[beg + i] : n;
    float4 av = as4[s];
    sm.x += __expf(leaky(av.x + adv.x) - mx.x);
    sm.y += __expf(leaky(av.y + adv.y) - mx.y);
    sm.z += __expf(leaky(av.z + adv.z) - mx.z);
    sm.w += __expf(leaky(av.w + adv.w) - mx.w);
  }
#pragma unroll
  for (int off = 32; off >= 1; off >>= 1) {
    sm.x += __shfl_xor(sm.x, off, 64);
    sm.y += __shfl_xor(sm.y, off, 64);
    sm.z += __shfl_xor(sm.z, off, 64);
    sm.w += __shfl_xor(sm.w, off, 64);
  }
  float4 inv;
  inv.x = 1.f / (sm.x + 1e-16f); inv.y = 1.f / (sm.y + 1e-16f);
  inv.z = 1.f / (sm.z + 1e-16f); inv.w = 1.f / (sm.w + 1e-16f);

  float4 acc0 = make_float4(0.f, 0.f, 0.f, 0.f);
  float4 acc1 = make_float4(0.f, 0.f, 0.f, 0.f);
  for (int base = 0; base < tot; base += 64) {
    int sl;
    float4 wl;
    if (base == 0) {
      sl = s0;
      wl.x = __expf(e0.x - mx.x) * inv.x;
      wl.y = __expf(e0.y - mx.y) * inv.y;
      wl.z = __expf(e0.z - mx.z) * inv.z;
      wl.w = __expf(e0.w - mx.w) * inv.w;
    } else {
      int i = base + lane;
      sl = n;
      wl = make_float4(0.f, 0.f, 0.f, 0.f);
      if (i < tot) {
        if (i < deg) sl = esrc[beg + i];
        float4 av = as4[sl];
        wl.x = __expf(leaky(av.x + adv.x) - mx.x) * inv.x;
        wl.y = __expf(leaky(av.y + adv.y) - mx.y) * inv.y;
        wl.z = __expf(leaky(av.z + adv.z) - mx.z) * inv.z;
        wl.w = __expf(leaky(av.w + adv.w) - mx.w) * inv.w;
      }
    }
    int m = min(64, tot - base);
    for (int j = 0; j < m; ++j) {
      int s = __builtin_amdgcn_readlane(sl, j);
      float wx = rdlanef(wl.x, j);
      float wy = rdlanef(wl.y, j);
      float wz = rdlanef(wl.z, j);
      float ww = rdlanef(wl.w, j);
      float wA = (lane < 32) ? wx : wy;  // heads 0/1
      float wB = (lane < 32) ? wz : ww;  // heads 2/3
      uint4 hv = h1p[(size_t)s * 64 + lane];
      acc0.x = fmaf(wA, bflo(hv.x), acc0.x);
      acc0.y = fmaf(wA, bfhi(hv.x), acc0.y);
      acc0.z = fmaf(wA, bflo(hv.y), acc0.z);
      acc0.w = fmaf(wA, bfhi(hv.y), acc0.w);
      acc1.x = fmaf(wB, bflo(hv.z), acc1.x);
      acc1.y = fmaf(wB, bfhi(hv.z), acc1.y);
      acc1.z = fmaf(wB, bflo(hv.w), acc1.z);
      acc1.w = fmaf(wB, bfhi(hv.w), acc1.w);
    }
  }
  float4 bA = ((const float4*)b1)[lane];
  float4 bB = ((const float4*)b1)[64 + lane];
  float4 r0, r1;
  r0.x = fmaxf(acc0.x + bA.x, 0.f); r0.y = fmaxf(acc0.y + bA.y, 0.f);
  r0.z = fmaxf(acc0.z + bA.z, 0.f); r0.w = fmaxf(acc0.w + bA.w, 0.f);
  r1.x = fmaxf(acc1.x + bB.x, 0.f); r1.y = fmaxf(acc1.y + bB.y, 0.f);
  r1.z = fmaxf(acc1.z + bB.z, 0.f); r1.w = fmaxf(acc1.w + bB.w, 0.f);
  ((float4*)(out1 + (size_t)n * 512))[lane] = r0;
  ((float4*)(out1 + (size_t)n * 512 + 256))[lane] = r1;
}

// ---------------- layer-2 softmax + aggregation: 1 wave per node ----------------
__global__ __launch_bounds__(256) void agg2_k(const int* __restrict__ rowstart,
                                              const int* __restrict__ esrc,
                                              const float* __restrict__ as,
                                              const float* __restrict__ ad,
                                              const unsigned* __restrict__ h2b,
                                              const float* __restrict__ b2,
                                              float* __restrict__ out2) {
  const int lane = threadIdx.x & 63;
  const int n = blockIdx.x * 4 + (threadIdx.x >> 6);
  const int beg = rowstart[n];
  const int deg = rowstart[n + 1] - beg;
  const int tot = deg + 1;
  const float adv = ad[n];

  int s0 = n;
  float e0 = -1e30f;
  if (lane < tot) {
    if (lane < deg) s0 = esrc[beg + lane];
    e0 = leaky(as[s0] + adv);
  }
  float mx = e0;
  for (int i = lane + 64; i < tot; i += 64) {
    int s = (i < deg) ? esrc[beg + i] : n;
    mx = fmaxf(mx, leaky(as[s] + adv));
  }
#pragma unroll
  for (int off = 32; off >= 1; off >>= 1) mx = fmaxf(mx, __shfl_xor(mx, off, 64));
  float sm = __expf(e0 - mx);
  for (int i = lane + 64; i < tot; i += 64) {
    int s = (i < deg) ? esrc[beg + i] : n;
    sm += __expf(leaky(as[s] + adv) - mx);
  }
#pragma unroll
  for (int off = 32; off >= 1; off >>= 1) sm += __shfl_xor(sm, off, 64);
  float inv = 1.f / (sm + 1e-16f);

  float2 acc = make_float2(0.f, 0.f);
  for (int base = 0; base < tot; base += 64) {
    int sl;
    float wl;
    if (base == 0) {
      sl = s0;
      wl = __expf(e0 - mx) * inv;
    } else {
      int i = base + lane;
      sl = n; wl = 0.f;
      if (i < tot) {
        if (i < deg) sl = esrc[beg + i];
        wl = __expf(leaky(as[sl] + adv) - mx) * inv;
      }
    }
    int m = min(64, tot - base);
    for (int j = 0; j < m; ++j) {
      int s = __builtin_amdgcn_readlane(sl, j);
      float w = rdlanef(wl, j);
      unsigned hv = h2b[(size_t)s * 64 + lane];
      acc.x = fmaf(w, bflo(hv), acc.x);
      acc.y = fmaf(w, bfhi(hv), acc.y);
    }
  }
  float2 bb = ((const float2*)b2)[lane];
  float2 r;
  r.x = fmaxf(acc.x + bb.x, 0.f);
  r.y = fmaxf(acc.y + bb.y, 0.f);
  ((float2*)(out2 + (size_t)n * 128))[lane] = r;
}

// ---------------- pooling + FC (one block per graph, no atomics) ----------------
__global__ __launch_bounds__(128) void poolfc_k(const int* __restrict__ gstart,
                                                const float* __restrict__ out2,
                                                const float* __restrict__ fcw,
                                                const float* __restrict__ fcb,
                                                float* __restrict__ out) {
  const int g = blockIdx.x;
  const int tid = threadIdx.x;
  const int beg = gstart[g], end = gstart[g + 1];
  const int cnt = end - beg;
  float acc = 0.f;
  int n = beg;
  for (; n + 4 <= end; n += 4) {
    float v0 = out2[(size_t)(n + 0) * 128 + tid];
    float v1 = out2[(size_t)(n + 1) * 128 + tid];
    float v2 = out2[(size_t)(n + 2) * 128 + tid];
    float v3 = out2[(size_t)(n + 3) * 128 + tid];
    acc += (v0 + v1) + (v2 + v3);
  }
  for (; n < end; n++) acc += out2[(size_t)n * 128 + tid];
  __shared__ float pg[128];
  pg[tid] = acc / (float)(cnt > 0 ? cnt : 1);
  __syncthreads();
  if (tid < 64) {
    float o = fcb[tid];
#pragma unroll 8
    for (int c = 0; c < 128; c++) o = fmaf(pg[c], fcw[c * 64 + tid], o);
    out[g * 64 + tid] = o;
  }
}

// ---------------- launch ----------------
extern "C" void kernel_launch(void* const* d_in, const int* in_sizes, int n_in,
                              void* d_out, int out_size, void* d_ws, size_t ws_size,
                              hipStream_t stream) {
  const float* x   = (const float*)d_in[0];
  const int*   ei  = (const int*)d_in[1];
  const int*   bat = (const int*)d_in[2];
  const float* W1  = (const float*)d_in[3];
  const float* a1s = (const float*)d_in[4];
  const float* a1d = (const float*)d_in[5];
  const float* b1  = (const float*)d_in[6];
  const float* W2  = (const float*)d_in[7];
  const float* a2s = (const float*)d_in[8];
  const float* a2d = (const float*)d_in[9];
  const float* b2  = (const float*)d_in[10];
  const float* fcw = (const float*)d_in[11];
  const float* fcb = (const float*)d_in[12];
  float* out = (float*)d_out;

  char* ws = (char*)d_ws;
  size_t off = 0;
  auto alloc = [&](size_t bytes) -> void* {
    void* p = ws + off;
    off = (off + bytes + 255) & ~(size_t)255;
    return p;
  };

  int*   count    = (int*)alloc((size_t)NN * 4);
  int*   rowstart = (int*)alloc((size_t)(NN + 1) * 4);
  int*   cursor   = (int*)alloc((size_t)NN * 4);
  int*   esrc     = (int*)alloc((size_t)EE * 4);
  int*   gstart   = (int*)alloc((size_t)(GG + 1) * 4);
  float* h1       = (float*)alloc((size_t)NN * 512 * 4);
  float* as1      = (float*)alloc((size_t)NN * 4 * 4);
  float* ad1      = (float*)alloc((size_t)NN * 4 * 4);
  float* out1     = (float*)alloc((size_t)NN * 512 * 4);
  float* h2       = (float*)alloc((size_t)NN * 128 * 4);
  float* as2      = (float*)alloc((size_t)NN * 4);
  float* ad2      = (float*)alloc((size_t)NN * 4);
  float* out2     = (float*)alloc((size_t)NN * 128 * 4);
  uint4* h1p      = (uint4*)alloc((size_t)NN * 512 * 2);
  unsigned* h2b   = (unsigned*)alloc((size_t)NN * 128 * 2);
  (void)ws_size; (void)in_sizes; (void)n_in; (void)out_size;

  zero_k<<<(NN + 255) / 256, 256, 0, stream>>>(count);
  hist_k<<<(EE + 255) / 256, 256, 0, stream>>>(ei, count);
  scan_k<<<1, 1024, 0, stream>>>(count, rowstart, cursor);
  fill_k<<<(EE + 255) / 256, 256, 0, stream>>>(ei, cursor, esrc);
  gstart_k<<<(NN + 255) / 256, 256, 0, stream>>>(bat, gstart);

  gemm_k<<<dim3(512 / 64, (NN + 63) / 64), 256, 0, stream>>>(x, W1, h1, NN, 256, 512);
  alpha1_k<<<NN, 256, 0, stream>>>(h1, a1s, a1d, as1, ad1);
  packh1_k<<<NN / 4, 256, 0, stream>>>(h1, h1p);
  agg1_k<<<NN / 4, 256, 0, stream>>>(rowstart, esrc, as1, ad1, h1p, b1, out1);

  gemm_k<<<dim3(128 / 64, (NN + 63) / 64), 256, 0, stream>>>(out1, W2, h2, NN, 512, 128);
  alpha2_k<<<NN, 64, 0, stream>>>(h2, a2s, a2d, as2, ad2);
  packh2_k<<<NN / 4, 256, 0, stream>>>(h2, h2b);
  agg2_k<<<NN / 4, 256, 0, stream>>>(rowstart, esrc, as2, ad2, h2b, b2, out2);

  poolfc_k<<<GG, 128, 0, stream>>>(gstart, out2, fcw, fcb, out);
}

// Round 4
// 218.777 us; speedup vs baseline: 1.6300x; 1.2447x over previous
//
#include <hip/hip_runtime.h>
#include <math.h>

#define NN 10000
#define EE 320000
#define GG 64
#define NT 157            // ceil(NN/64)
#define NPAD (NT * 64)    // 10048

typedef __attribute__((ext_vector_type(8))) short short8;
typedef __attribute__((ext_vector_type(4))) float f32x4;

__device__ __forceinline__ float leaky(float x) { return x >= 0.f ? x : 0.2f * x; }

__device__ __forceinline__ unsigned f2bf(float f) {
  unsigned u = __float_as_uint(f);
  return (u + 0x7fffu + ((u >> 16) & 1u)) >> 16;
}
__device__ __forceinline__ float bflo(unsigned v) { return __uint_as_float(v << 16); }
__device__ __forceinline__ float bfhi(unsigned v) { return __uint_as_float(v & 0xffff0000u); }
__device__ __forceinline__ float rdlanef(float v, int j) {
  return __uint_as_float(__builtin_amdgcn_readlane(__float_as_uint(v), j));
}

// ---------------- setup kernels ----------------
__global__ __launch_bounds__(256) void zero_k(int* __restrict__ count) {
  int i = blockIdx.x * 256 + threadIdx.x;
  if (i < NN) count[i] = 0;
}

__global__ __launch_bounds__(256) void hist_k(const int* __restrict__ ei,
                                              int* __restrict__ count) {
  int e = blockIdx.x * 256 + threadIdx.x;
  if (e < EE) atomicAdd(&count[ei[EE + e]], 1);
}

__global__ __launch_bounds__(1024) void scan_k(const int* __restrict__ count,
                                               int* __restrict__ rowstart,
                                               int* __restrict__ cursor) {
  __shared__ int part[1024];
  const int tid = threadIdx.x;
  const int PER = (NN + 1023) / 1024;  // 10
  int base = tid * PER;
  int local[PER];
  int s = 0;
#pragma unroll
  for (int i = 0; i < PER; i++) {
    int idx = base + i;
    int v = (idx < NN) ? count[idx] : 0;
    local[i] = s;
    s += v;
  }
  part[tid] = s;
  __syncthreads();
  for (int off = 1; off < 1024; off <<= 1) {
    int v = (tid >= off) ? part[tid - off] : 0;
    __syncthreads();
    part[tid] += v;
    __syncthreads();
  }
  int pre = (tid == 0) ? 0 : part[tid - 1];
#pragma unroll
  for (int i = 0; i < PER; i++) {
    int idx = base + i;
    if (idx < NN) { int v = pre + local[i]; rowstart[idx] = v; cursor[idx] = v; }
  }
  if (tid == 1023) rowstart[NN] = part[1023];
}

__global__ __launch_bounds__(256) void fill_k(const int* __restrict__ ei,
                                              int* __restrict__ cursor,
                                              int* __restrict__ esrc) {
  int e = blockIdx.x * 256 + threadIdx.x;
  if (e < EE) {
    int d = ei[EE + e];
    int pos = atomicAdd(&cursor[d], 1);
    esrc[pos] = ei[e];
  }
}

__global__ __launch_bounds__(256) void gstart_k(const int* __restrict__ batch,
                                                int* __restrict__ gstart) {
  int i = blockIdx.x * 256 + threadIdx.x;
  if (i >= NN) return;
  int b = batch[i];
  int prev = (i == 0) ? -1 : batch[i - 1];
  for (int g = prev + 1; g <= b; g++) gstart[g] = i;
  if (i == NN - 1)
    for (int g = b + 1; g <= GG; g++) gstart[g] = NN;
}

// ---------------- pack kernels ----------------
// x f32 [NN][256] -> bf16 [NPAD][256] (rows >= NN left as garbage, never used validly)
__global__ __launch_bounds__(256) void packx_k(const float* __restrict__ x,
                                               uint4* __restrict__ xb) {
  int idx = blockIdx.x * 256 + threadIdx.x;  // one uint4 = 8 bf16
  if (idx >= NN * 256 / 8) return;
  const float4* xf = (const float4*)x;
  float4 a = xf[idx * 2], b = xf[idx * 2 + 1];
  uint4 o;
  o.x = f2bf(a.x) | (f2bf(a.y) << 16);
  o.y = f2bf(a.z) | (f2bf(a.w) << 16);
  o.z = f2bf(b.x) | (f2bf(b.y) << 16);
  o.w = f2bf(b.z) | (f2bf(b.w) << 16);
  xb[idx] = o;
}

// W [K][C] f32 -> wt hi/lo bf16 [C][K] (transposed, split into hi + residual lo)
__global__ __launch_bounds__(256) void packwt_k(const float* __restrict__ W,
                                                ushort* __restrict__ hi,
                                                ushort* __restrict__ lo,
                                                int K, int C) {
  int idx = blockIdx.x * 256 + threadIdx.x;  // idx = c*K + k
  if (idx >= K * C) return;
  int c = idx / K, k = idx - c * K;
  float w = W[(size_t)k * C + c];
  unsigned h = f2bf(w);
  float r = w - __uint_as_float(h << 16);
  hi[idx] = (ushort)h;
  lo[idx] = (ushort)f2bf(r);
}

// ---------------- MFMA GEMM, transposed output ----------------
// O[node][ch] (bf16 packed) = sum_k A[node][k] * W[k][ch]
// inputs: ab = A rows bf16 [NPAD][K]; whi/wlo = W^T bf16 [C][K] (hi+lo split)
// grid: (C/64, NT), block 256 (4 waves, each wave: 16 ch x 64 nodes)
__global__ __launch_bounds__(256) void gemmt_k(const ushort* __restrict__ ab,
                                               const ushort* __restrict__ whi,
                                               const ushort* __restrict__ wlo,
                                               unsigned* __restrict__ op,
                                               int K, int C) {
  const int lane = threadIdx.x & 63;
  const int wave = threadIdx.x >> 6;
  const int l15 = lane & 15;
  const int kg = lane >> 4;                      // 0..3 (k-group of 8)
  const int ch0 = blockIdx.x * 64 + wave * 16;   // wave's 16-channel row block
  const int node0 = blockIdx.y * 64;
  const ushort* arow_hi = whi + (size_t)(ch0 + l15) * K + kg * 8;
  const ushort* arow_lo = wlo + (size_t)(ch0 + l15) * K + kg * 8;
  const ushort* brow = ab + (size_t)(node0 + l15) * K + kg * 8;
  f32x4 acc[4];
#pragma unroll
  for (int f = 0; f < 4; f++) acc[f] = (f32x4){0.f, 0.f, 0.f, 0.f};
  for (int k0 = 0; k0 < K; k0 += 32) {
    short8 ah = *(const short8*)(arow_hi + k0);
    short8 al = *(const short8*)(arow_lo + k0);
#pragma unroll
    for (int f = 0; f < 4; f++) {
      short8 bv = *(const short8*)(brow + (size_t)f * 16 * K + k0);
      acc[f] = __builtin_amdgcn_mfma_f32_16x16x32_bf16(ah, bv, acc[f], 0, 0, 0);
      acc[f] = __builtin_amdgcn_mfma_f32_16x16x32_bf16(al, bv, acc[f], 0, 0, 0);
    }
  }
  const int chw = ch0 + kg * 4;  // 4 consecutive channels owned by this lane
#pragma unroll
  for (int f = 0; f < 4; f++) {
    int node = node0 + f * 16 + l15;
    unsigned u0 = f2bf(acc[f][0]) | (f2bf(acc[f][1]) << 16);
    unsigned u1 = f2bf(acc[f][2]) | (f2bf(acc[f][3]) << 16);
    *(uint2*)(op + (size_t)node * (C >> 1) + (chw >> 1)) = make_uint2(u0, u1);
  }
}

// ---------------- alpha dots (from packed bf16) ----------------
__global__ __launch_bounds__(256) void alpha1b_k(const uint4* __restrict__ h1p,
                                                 const float* __restrict__ a1s,
                                                 const float* __restrict__ a1d,
                                                 float* __restrict__ as1,
                                                 float* __restrict__ ad1) {
  int lane = threadIdx.x & 63;
  int n = blockIdx.x * 4 + (threadIdx.x >> 6);
  uint4 hv = h1p[(size_t)n * 64 + lane];
  const float4* s4 = (const float4*)a1s;
  const float4* d4 = (const float4*)a1d;
  float4 sa = s4[2 * lane], sb = s4[2 * lane + 1];
  float4 da = d4[2 * lane], db = d4[2 * lane + 1];
  float h0 = bflo(hv.x), h1 = bfhi(hv.x), h2 = bflo(hv.y), h3 = bfhi(hv.y);
  float h4 = bflo(hv.z), h5 = bfhi(hv.z), h6 = bflo(hv.w), h7 = bfhi(hv.w);
  float ss = h0 * sa.x + h1 * sa.y + h2 * sa.z + h3 * sa.w +
             h4 * sb.x + h5 * sb.y + h6 * sb.z + h7 * sb.w;
  float sd = h0 * da.x + h1 * da.y + h2 * da.z + h3 * da.w +
             h4 * db.x + h5 * db.y + h6 * db.z + h7 * db.w;
#pragma unroll
  for (int off = 8; off >= 1; off >>= 1) {
    ss += __shfl_xor(ss, off, 64);
    sd += __shfl_xor(sd, off, 64);
  }
  if ((lane & 15) == 0) {
    as1[n * 4 + (lane >> 4)] = ss;
    ad1[n * 4 + (lane >> 4)] = sd;
  }
}

__global__ __launch_bounds__(256) void alpha2b_k(const unsigned* __restrict__ h2p,
                                                 const float* __restrict__ a2s,
                                                 const float* __restrict__ a2d,
                                                 float* __restrict__ as2,
                                                 float* __restrict__ ad2) {
  int lane = threadIdx.x & 63;
  int n = blockIdx.x * 4 + (threadIdx.x >> 6);
  unsigned hv = h2p[(size_t)n * 64 + lane];
  float2 sa = ((const float2*)a2s)[lane];
  float2 da = ((const float2*)a2d)[lane];
  float ss = bflo(hv) * sa.x + bfhi(hv) * sa.y;
  float sd = bflo(hv) * da.x + bfhi(hv) * da.y;
#pragma unroll
  for (int off = 32; off >= 1; off >>= 1) {
    ss += __shfl_xor(ss, off, 64);
    sd += __shfl_xor(sd, off, 64);
  }
  if (lane == 0) { as2[n] = ss; ad2[n] = sd; }
}

// ---------------- layer-1 softmax + aggregation: 1 wave per node ----------------
// h1p natural layout: lane owns channels [8*lane, 8*lane+8) -> single head per lane
// writes out1 directly as bf16 (o1b), the layer-2 GEMM A-operand
__global__ __launch_bounds__(256) void agg1_k(const int* __restrict__ rowstart,
                                              const int* __restrict__ esrc,
                                              const float* __restrict__ as,
                                              const float* __restrict__ ad,
                                              const uint4* __restrict__ h1p,
                                              const float* __restrict__ b1,
                                              uint4* __restrict__ o1b) {
  const int lane = threadIdx.x & 63;
  const int n = blockIdx.x * 4 + (threadIdx.x >> 6);
  const int beg = rowstart[n];
  const int deg = rowstart[n + 1] - beg;
  const int tot = deg + 1;  // + self loop
  const float4* as4 = (const float4*)as;
  const float4 adv = ((const float4*)ad)[n];

  int s0 = n;
  float4 e0 = make_float4(-1e30f, -1e30f, -1e30f, -1e30f);
  if (lane < tot) {
    if (lane < deg) s0 = esrc[beg + lane];
    float4 av = as4[s0];
    e0.x = leaky(av.x + adv.x); e0.y = leaky(av.y + adv.y);
    e0.z = leaky(av.z + adv.z); e0.w = leaky(av.w + adv.w);
  }
  float4 mx = e0;
  for (int i = lane + 64; i < tot; i += 64) {
    int s = (i < deg) ? esrc[beg + i] : n;
    float4 av = as4[s];
    mx.x = fmaxf(mx.x, leaky(av.x + adv.x));
    mx.y = fmaxf(mx.y, leaky(av.y + adv.y));
    mx.z = fmaxf(mx.z, leaky(av.z + adv.z));
    mx.w = fmaxf(mx.w, leaky(av.w + adv.w));
  }
#pragma unroll
  for (int off = 32; off >= 1; off >>= 1) {
    mx.x = fmaxf(mx.x, __shfl_xor(mx.x, off, 64));
    mx.y = fmaxf(mx.y, __shfl_xor(mx.y, off, 64));
    mx.z = fmaxf(mx.z, __shfl_xor(mx.z, off, 64));
    mx.w = fmaxf(mx.w, __shfl_xor(mx.w, off, 64));
  }
  float4 sm;
  sm.x = __expf(e0.x - mx.x); sm.y = __expf(e0.y - mx.y);
  sm.z = __expf(e0.z - mx.z); sm.w = __expf(e0.w - mx.w);
  for (int i = lane + 64; i < tot; i += 64) {
    int s = (i < deg) ? esrc[beg + i] : n;
    float4 av = as4[s];
    sm.x += __expf(leaky(av.x + adv.x) - mx.x);
    sm.y += __expf(leaky(av.y + adv.y) - mx.y);
    sm.z += __expf(leaky(av.z + adv.z) - mx.z);
    sm.w += __expf(leaky(av.w + adv.w) - mx.w);
  }
#pragma unroll
  for (int off = 32; off >= 1; off >>= 1) {
    sm.x += __shfl_xor(sm.x, off, 64);
    sm.y += __shfl_xor(sm.y, off, 64);
    sm.z += __shfl_xor(sm.z, off, 64);
    sm.w += __shfl_xor(sm.w, off, 64);
  }
  float4 inv;
  inv.x = 1.f / (sm.x + 1e-16f); inv.y = 1.f / (sm.y + 1e-16f);
  inv.z = 1.f / (sm.z + 1e-16f); inv.w = 1.f / (sm.w + 1e-16f);

  float4 acc0 = make_float4(0.f, 0.f, 0.f, 0.f);
  float4 acc1 = make_float4(0.f, 0.f, 0.f, 0.f);
  for (int base = 0; base < tot; base += 64) {
    int sl;
    float4 wl;
    if (base == 0) {
      sl = s0;
      wl.x = __expf(e0.x - mx.x) * inv.x;
      wl.y = __expf(e0.y - mx.y) * inv.y;
      wl.z = __expf(e0.z - mx.z) * inv.z;
      wl.w = __expf(e0.w - mx.w) * inv.w;
    } else {
      int i = base + lane;
      sl = n;
      wl = make_float4(0.f, 0.f, 0.f, 0.f);
      if (i < tot) {
        if (i < deg) sl = esrc[beg + i];
        float4 av = as4[sl];
        wl.x = __expf(leaky(av.x + adv.x) - mx.x) * inv.x;
        wl.y = __expf(leaky(av.y + adv.y) - mx.y) * inv.y;
        wl.z = __expf(leaky(av.z + adv.z) - mx.z) * inv.z;
        wl.w = __expf(leaky(av.w + adv.w) - mx.w) * inv.w;
      }
    }
    int m = min(64, tot - base);
    for (int j = 0; j < m; ++j) {
      int s = __builtin_amdgcn_readlane(sl, j);
      float wx = rdlanef(wl.x, j);
      float wy = rdlanef(wl.y, j);
      float wz = rdlanef(wl.z, j);
      float ww = rdlanef(wl.w, j);
      // lane's 8 channels all belong to head = lane>>4
      float w = (lane < 32) ? ((lane < 16) ? wx : wy) : ((lane < 48) ? wz : ww);
      uint4 hv = h1p[(size_t)s * 64 + lane];
      acc0.x = fmaf(w, bflo(hv.x), acc0.x);
      acc0.y = fmaf(w, bfhi(hv.x), acc0.y);
      acc0.z = fmaf(w, bflo(hv.y), acc0.z);
      acc0.w = fmaf(w, bfhi(hv.y), acc0.w);
      acc1.x = fmaf(w, bflo(hv.z), acc1.x);
      acc1.y = fmaf(w, bfhi(hv.z), acc1.y);
      acc1.z = fmaf(w, bflo(hv.w), acc1.z);
      acc1.w = fmaf(w, bfhi(hv.w), acc1.w);
    }
  }
  const float4* b4 = (const float4*)b1;
  float4 ba = b4[2 * lane], bb = b4[2 * lane + 1];
  float4 r0, r1;
  r0.x = fmaxf(acc0.x + ba.x, 0.f); r0.y = fmaxf(acc0.y + ba.y, 0.f);
  r0.z = fmaxf(acc0.z + ba.z, 0.f); r0.w = fmaxf(acc0.w + ba.w, 0.f);
  r1.x = fmaxf(acc1.x + bb.x, 0.f); r1.y = fmaxf(acc1.y + bb.y, 0.f);
  r1.z = fmaxf(acc1.z + bb.z, 0.f); r1.w = fmaxf(acc1.w + bb.w, 0.f);
  uint4 o;
  o.x = f2bf(r0.x) | (f2bf(r0.y) << 16);
  o.y = f2bf(r0.z) | (f2bf(r0.w) << 16);
  o.z = f2bf(r1.x) | (f2bf(r1.y) << 16);
  o.w = f2bf(r1.z) | (f2bf(r1.w) << 16);
  o1b[(size_t)n * 64 + lane] = o;
}

// ---------------- layer-2 softmax + aggregation: 1 wave per node ----------------
__global__ __launch_bounds__(256) void agg2_k(const int* __restrict__ rowstart,
                                              const int* __restrict__ esrc,
                                              const float* __restrict__ as,
                                              const float* __restrict__ ad,
                                              const unsigned* __restrict__ h2p,
                                              const float* __restrict__ b2,
                                              float* __restrict__ out2) {
  const int lane = threadIdx.x & 63;
  const int n = blockIdx.x * 4 + (threadIdx.x >> 6);
  const int beg = rowstart[n];
  const int deg = rowstart[n + 1] - beg;
  const int tot = deg + 1;
  const float adv = ad[n];

  int s0 = n;
  float e0 = -1e30f;
  if (lane < tot) {
    if (lane < deg) s0 = esrc[beg + lane];
    e0 = leaky(as[s0] + adv);
  }
  float mx = e0;
  for (int i = lane + 64; i < tot; i += 64) {
    int s = (i < deg) ? esrc[beg + i] : n;
    mx = fmaxf(mx, leaky(as[s] + adv));
  }
#pragma unroll
  for (int off = 32; off >= 1; off >>= 1) mx = fmaxf(mx, __shfl_xor(mx, off, 64));
  float sm = __expf(e0 - mx);
  for (int i = lane + 64; i < tot; i += 64) {
    int s = (i < deg) ? esrc[beg + i] : n;
    sm += __expf(leaky(as[s] + adv) - mx);
  }
#pragma unroll
  for (int off = 32; off >= 1; off >>= 1) sm += __shfl_xor(sm, off, 64);
  float inv = 1.f / (sm + 1e-16f);

  float2 acc = make_float2(0.f, 0.f);
  for (int base = 0; base < tot; base += 64) {
    int sl;
    float wl;
    if (base == 0) {
      sl = s0;
      wl = __expf(e0 - mx) * inv;
    } else {
      int i = base + lane;
      sl = n; wl = 0.f;
      if (i < tot) {
        if (i < deg) sl = esrc[beg + i];
        wl = __expf(leaky(as[sl] + adv) - mx) * inv;
      }
    }
    int m = min(64, tot - base);
    for (int j = 0; j < m; ++j) {
      int s = __builtin_amdgcn_readlane(sl, j);
      float w = rdlanef(wl, j);
      unsigned hv = h2p[(size_t)s * 64 + lane];
      acc.x = fmaf(w, bflo(hv), acc.x);
      acc.y = fmaf(w, bfhi(hv), acc.y);
    }
  }
  float2 bb = ((const float2*)b2)[lane];
  float2 r;
  r.x = fmaxf(acc.x + bb.x, 0.f);
  r.y = fmaxf(acc.y + bb.y, 0.f);
  ((float2*)(out2 + (size_t)n * 128))[lane] = r;
}

// ---------------- pooling + FC (one block per graph, no atomics) ----------------
__global__ __launch_bounds__(128) void poolfc_k(const int* __restrict__ gstart,
                                                const float* __restrict__ out2,
                                                const float* __restrict__ fcw,
                                                const float* __restrict__ fcb,
                                                float* __restrict__ out) {
  const int g = blockIdx.x;
  const int tid = threadIdx.x;
  const int beg = gstart[g], end = gstart[g + 1];
  const int cnt = end - beg;
  float acc = 0.f;
  int n = beg;
  for (; n + 4 <= end; n += 4) {
    float v0 = out2[(size_t)(n + 0) * 128 + tid];
    float v1 = out2[(size_t)(n + 1) * 128 + tid];
    float v2 = out2[(size_t)(n + 2) * 128 + tid];
    float v3 = out2[(size_t)(n + 3) * 128 + tid];
    acc += (v0 + v1) + (v2 + v3);
  }
  for (; n < end; n++) acc += out2[(size_t)n * 128 + tid];
  __shared__ float pg[128];
  pg[tid] = acc / (float)(cnt > 0 ? cnt : 1);
  __syncthreads();
  if (tid < 64) {
    float o = fcb[tid];
#pragma unroll 8
    for (int c = 0; c < 128; c++) o = fmaf(pg[c], fcw[c * 64 + tid], o);
    out[g * 64 + tid] = o;
  }
}

// ---------------- launch ----------------
extern "C" void kernel_launch(void* const* d_in, const int* in_sizes, int n_in,
                              void* d_out, int out_size, void* d_ws, size_t ws_size,
                              hipStream_t stream) {
  const float* x   = (const float*)d_in[0];
  const int*   ei  = (const int*)d_in[1];
  const int*   bat = (const int*)d_in[2];
  const float* W1  = (const float*)d_in[3];
  const float* a1s = (const float*)d_in[4];
  const float* a1d = (const float*)d_in[5];
  const float* b1  = (const float*)d_in[6];
  const float* W2  = (const float*)d_in[7];
  const float* a2s = (const float*)d_in[8];
  const float* a2d = (const float*)d_in[9];
  const float* b2  = (const float*)d_in[10];
  const float* fcw = (const float*)d_in[11];
  const float* fcb = (const float*)d_in[12];
  float* out = (float*)d_out;

  char* ws = (char*)d_ws;
  size_t off = 0;
  auto alloc = [&](size_t bytes) -> void* {
    void* p = ws + off;
    off = (off + bytes + 255) & ~(size_t)255;
    return p;
  };

  int*   count    = (int*)alloc((size_t)NN * 4);
  int*   rowstart = (int*)alloc((size_t)(NN + 1) * 4);
  int*   cursor   = (int*)alloc((size_t)NN * 4);
  int*   esrc     = (int*)alloc((size_t)EE * 4);
  int*   gstart   = (int*)alloc((size_t)(GG + 1) * 4);
  ushort* xb      = (ushort*)alloc((size_t)NPAD * 256 * 2);
  ushort* w1hi    = (ushort*)alloc((size_t)512 * 256 * 2);
  ushort* w1lo    = (ushort*)alloc((size_t)512 * 256 * 2);
  ushort* w2hi    = (ushort*)alloc((size_t)128 * 512 * 2);
  ushort* w2lo    = (ushort*)alloc((size_t)128 * 512 * 2);
  ushort* h1p     = (ushort*)alloc((size_t)NPAD * 512 * 2);
  ushort* o1b     = (ushort*)alloc((size_t)NPAD * 512 * 2);
  ushort* h2p     = (ushort*)alloc((size_t)NPAD * 128 * 2);
  float* as1      = (float*)alloc((size_t)NN * 4 * 4);
  float* ad1      = (float*)alloc((size_t)NN * 4 * 4);
  float* as2      = (float*)alloc((size_t)NN * 4);
  float* ad2      = (float*)alloc((size_t)NN * 4);
  float* out2     = (float*)alloc((size_t)NN * 128 * 4);
  (void)ws_size; (void)in_sizes; (void)n_in; (void)out_size;

  zero_k<<<(NN + 255) / 256, 256, 0, stream>>>(count);
  hist_k<<<(EE + 255) / 256, 256, 0, stream>>>(ei, count);
  scan_k<<<1, 1024, 0, stream>>>(count, rowstart, cursor);
  fill_k<<<(EE + 255) / 256, 256, 0, stream>>>(ei, cursor, esrc);
  gstart_k<<<(NN + 255) / 256, 256, 0, stream>>>(bat, gstart);

  packx_k<<<(NN * 256 / 8 + 255) / 256, 256, 0, stream>>>(x, (uint4*)xb);
  packwt_k<<<(256 * 512 + 255) / 256, 256, 0, stream>>>(W1, w1hi, w1lo, 256, 512);
  packwt_k<<<(512 * 128 + 255) / 256, 256, 0, stream>>>(W2, w2hi, w2lo, 512, 128);

  gemmt_k<<<dim3(512 / 64, NT), 256, 0, stream>>>(xb, w1hi, w1lo, (unsigned*)h1p, 256, 512);
  alpha1b_k<<<NN / 4, 256, 0, stream>>>((const uint4*)h1p, a1s, a1d, as1, ad1);
  agg1_k<<<NN / 4, 256, 0, stream>>>(rowstart, esrc, as1, ad1, (const uint4*)h1p, b1,
                                     (uint4*)o1b);

  gemmt_k<<<dim3(128 / 64, NT), 256, 0, stream>>>(o1b, w2hi, w2lo, (unsigned*)h2p, 512, 128);
  alpha2b_k<<<NN / 4, 256, 0, stream>>>((const unsigned*)h2p, a2s, a2d, as2, ad2);
  agg2_k<<<NN / 4, 256, 0, stream>>>(rowstart, esrc, as2, ad2, (const unsigned*)h2p, b2, out2);

  poolfc_k<<<GG, 128, 0, stream>>>(gstart, out2, fcw, fcb, out);
}

// Round 5
// 202.642 us; speedup vs baseline: 1.7598x; 1.0796x over previous
//
#include <hip/hip_runtime.h>
#include <math.h>

#define NN 10000
#define EE 320000
#define GG 64
#define NT 157            // ceil(NN/64)
#define NPAD (NT * 64)    // 10048

typedef __attribute__((ext_vector_type(8))) short short8;
typedef __attribute__((ext_vector_type(4))) float f32x4;

__device__ __forceinline__ float leaky(float x) { return x >= 0.f ? x : 0.2f * x; }

__device__ __forceinline__ unsigned f2bf(float f) {
  unsigned u = __float_as_uint(f);
  return (u + 0x7fffu + ((u >> 16) & 1u)) >> 16;
}
__device__ __forceinline__ float bflo(unsigned v) { return __uint_as_float(v << 16); }
__device__ __forceinline__ float bfhi(unsigned v) { return __uint_as_float(v & 0xffff0000u); }

// ---------------- setup kernels ----------------
__global__ __launch_bounds__(256) void hist_k(const int* __restrict__ ei,
                                              int* __restrict__ count) {
  int e = blockIdx.x * 256 + threadIdx.x;
  if (e < EE) atomicAdd(&count[ei[EE + e]], 1);
}

__global__ __launch_bounds__(1024) void scan_k(const int* __restrict__ count,
                                               int* __restrict__ rowstart,
                                               int* __restrict__ cursor) {
  __shared__ int part[1024];
  const int tid = threadIdx.x;
  const int PER = (NN + 1023) / 1024;  // 10
  int base = tid * PER;
  int local[PER];
  int s = 0;
#pragma unroll
  for (int i = 0; i < PER; i++) {
    int idx = base + i;
    int v = (idx < NN) ? count[idx] : 0;
    local[i] = s;
    s += v;
  }
  part[tid] = s;
  __syncthreads();
  for (int off = 1; off < 1024; off <<= 1) {
    int v = (tid >= off) ? part[tid - off] : 0;
    __syncthreads();
    part[tid] += v;
    __syncthreads();
  }
  int pre = (tid == 0) ? 0 : part[tid - 1];
#pragma unroll
  for (int i = 0; i < PER; i++) {
    int idx = base + i;
    if (idx < NN) { int v = pre + local[i]; rowstart[idx] = v; cursor[idx] = v; }
  }
  if (tid == 1023) rowstart[NN] = part[1023];
}

__global__ __launch_bounds__(256) void fill_k(const int* __restrict__ ei,
                                              int* __restrict__ cursor,
                                              int* __restrict__ esrc) {
  int e = blockIdx.x * 256 + threadIdx.x;
  if (e < EE) {
    int d = ei[EE + e];
    int pos = atomicAdd(&cursor[d], 1);
    esrc[pos] = ei[e];
  }
}

__global__ __launch_bounds__(256) void gstart_k(const int* __restrict__ batch,
                                                int* __restrict__ gstart) {
  int i = blockIdx.x * 256 + threadIdx.x;
  if (i >= NN) return;
  int b = batch[i];
  int prev = (i == 0) ? -1 : batch[i - 1];
  for (int g = prev + 1; g <= b; g++) gstart[g] = i;
  if (i == NN - 1)
    for (int g = b + 1; g <= GG; g++) gstart[g] = NN;
}

// ---------------- fused pack kernel ----------------
#define PX_ITEMS (NN * 256 / 8)   // 320000 uint4 items
#define PW1 (512 * 256)           // 131072
#define PW2 (128 * 512)           // 65536
__global__ __launch_bounds__(256) void packall_k(const float* __restrict__ x,
                                                 const float* __restrict__ W1,
                                                 const float* __restrict__ W2,
                                                 uint4* __restrict__ xb,
                                                 ushort* __restrict__ w1hi,
                                                 ushort* __restrict__ w1lo,
                                                 ushort* __restrict__ w2hi,
                                                 ushort* __restrict__ w2lo) {
  int idx = blockIdx.x * 256 + threadIdx.x;
  if (idx < PX_ITEMS) {
    const float4* xf = (const float4*)x;
    float4 a = xf[idx * 2], b = xf[idx * 2 + 1];
    uint4 o;
    o.x = f2bf(a.x) | (f2bf(a.y) << 16);
    o.y = f2bf(a.z) | (f2bf(a.w) << 16);
    o.z = f2bf(b.x) | (f2bf(b.y) << 16);
    o.w = f2bf(b.z) | (f2bf(b.w) << 16);
    xb[idx] = o;
  } else if (idx < PX_ITEMS + PW1) {
    int i = idx - PX_ITEMS;            // i = c*256 + k
    int c = i >> 8, k = i & 255;
    float w = W1[(size_t)k * 512 + c];
    unsigned h = f2bf(w);
    float r = w - __uint_as_float(h << 16);
    w1hi[i] = (ushort)h;
    w1lo[i] = (ushort)f2bf(r);
  } else if (idx < PX_ITEMS + PW1 + PW2) {
    int i = idx - PX_ITEMS - PW1;      // i = c*512 + k
    int c = i >> 9, k = i & 511;
    float w = W2[(size_t)k * 128 + c];
    unsigned h = f2bf(w);
    float r = w - __uint_as_float(h << 16);
    w2hi[i] = (ushort)h;
    w2lo[i] = (ushort)f2bf(r);
  }
}

// ---------------- MFMA GEMM, transposed output ----------------
__global__ __launch_bounds__(256) void gemmt_k(const ushort* __restrict__ ab,
                                               const ushort* __restrict__ whi,
                                               const ushort* __restrict__ wlo,
                                               unsigned* __restrict__ op,
                                               int K, int C) {
  const int lane = threadIdx.x & 63;
  const int wave = threadIdx.x >> 6;
  const int l15 = lane & 15;
  const int kg = lane >> 4;                      // 0..3 (k-group of 8)
  const int ch0 = blockIdx.x * 64 + wave * 16;   // wave's 16-channel row block
  const int node0 = blockIdx.y * 64;
  const ushort* arow_hi = whi + (size_t)(ch0 + l15) * K + kg * 8;
  const ushort* arow_lo = wlo + (size_t)(ch0 + l15) * K + kg * 8;
  const ushort* brow = ab + (size_t)(node0 + l15) * K + kg * 8;
  f32x4 acc[4];
#pragma unroll
  for (int f = 0; f < 4; f++) acc[f] = (f32x4){0.f, 0.f, 0.f, 0.f};
  for (int k0 = 0; k0 < K; k0 += 32) {
    short8 ah = *(const short8*)(arow_hi + k0);
    short8 al = *(const short8*)(arow_lo + k0);
#pragma unroll
    for (int f = 0; f < 4; f++) {
      short8 bv = *(const short8*)(brow + (size_t)f * 16 * K + k0);
      acc[f] = __builtin_amdgcn_mfma_f32_16x16x32_bf16(ah, bv, acc[f], 0, 0, 0);
      acc[f] = __builtin_amdgcn_mfma_f32_16x16x32_bf16(al, bv, acc[f], 0, 0, 0);
    }
  }
  const int chw = ch0 + kg * 4;  // 4 consecutive channels owned by this lane
#pragma unroll
  for (int f = 0; f < 4; f++) {
    int node = node0 + f * 16 + l15;
    unsigned u0 = f2bf(acc[f][0]) | (f2bf(acc[f][1]) << 16);
    unsigned u1 = f2bf(acc[f][2]) | (f2bf(acc[f][3]) << 16);
    *(uint2*)(op + (size_t)node * (C >> 1) + (chw >> 1)) = make_uint2(u0, u1);
  }
}

// ---------------- alpha dots (from packed bf16) ----------------
__global__ __launch_bounds__(256) void alpha1b_k(const uint4* __restrict__ h1p,
                                                 const float* __restrict__ a1s,
                                                 const float* __restrict__ a1d,
                                                 float* __restrict__ as1,
                                                 float* __restrict__ ad1) {
  int lane = threadIdx.x & 63;
  int n = blockIdx.x * 4 + (threadIdx.x >> 6);
  uint4 hv = h1p[(size_t)n * 64 + lane];
  const float4* s4 = (const float4*)a1s;
  const float4* d4 = (const float4*)a1d;
  float4 sa = s4[2 * lane], sb = s4[2 * lane + 1];
  float4 da = d4[2 * lane], db = d4[2 * lane + 1];
  float h0 = bflo(hv.x), h1 = bfhi(hv.x), h2 = bflo(hv.y), h3 = bfhi(hv.y);
  float h4 = bflo(hv.z), h5 = bfhi(hv.z), h6 = bflo(hv.w), h7 = bfhi(hv.w);
  float ss = h0 * sa.x + h1 * sa.y + h2 * sa.z + h3 * sa.w +
             h4 * sb.x + h5 * sb.y + h6 * sb.z + h7 * sb.w;
  float sd = h0 * da.x + h1 * da.y + h2 * da.z + h3 * da.w +
             h4 * db.x + h5 * db.y + h6 * db.z + h7 * db.w;
#pragma unroll
  for (int off = 8; off >= 1; off >>= 1) {
    ss += __shfl_xor(ss, off, 64);
    sd += __shfl_xor(sd, off, 64);
  }
  if ((lane & 15) == 0) {
    as1[n * 4 + (lane >> 4)] = ss;
    ad1[n * 4 + (lane >> 4)] = sd;
  }
}

__global__ __launch_bounds__(256) void alpha2b_k(const unsigned* __restrict__ h2p,
                                                 const float* __restrict__ a2s,
                                                 const float* __restrict__ a2d,
                                                 float* __restrict__ as2,
                                                 float* __restrict__ ad2) {
  int lane = threadIdx.x & 63;
  int n = blockIdx.x * 4 + (threadIdx.x >> 6);
  unsigned hv = h2p[(size_t)n * 64 + lane];
  float2 sa = ((const float2*)a2s)[lane];
  float2 da = ((const float2*)a2d)[lane];
  float ss = bflo(hv) * sa.x + bfhi(hv) * sa.y;
  float sd = bflo(hv) * da.x + bfhi(hv) * da.y;
#pragma unroll
  for (int off = 32; off >= 1; off >>= 1) {
    ss += __shfl_xor(ss, off, 64);
    sd += __shfl_xor(sd, off, 64);
  }
  if (lane == 0) { as2[n] = ss; ad2[n] = sd; }
}

// ---------------- layer-1 softmax + aggregation: 1 wave per node ----------------
__global__ __launch_bounds__(256) void agg1_k(const int* __restrict__ rowstart,
                                              const int* __restrict__ esrc,
                                              const float* __restrict__ as,
                                              const float* __restrict__ ad,
                                              const ushort* __restrict__ h1p,
                                              const float* __restrict__ b1,
                                              uint4* __restrict__ o1b) {
  const int lane = threadIdx.x & 63;
  const int wid = threadIdx.x >> 6;
  const int n = blockIdx.x * 4 + wid;
  const int beg = rowstart[n];
  const int deg = rowstart[n + 1] - beg;
  const int tot = deg + 1;  // + self loop
  const float4* as4 = (const float4*)as;
  const float4 adv = ((const float4*)ad)[n];
  const int head = lane >> 4;

  __shared__ float wlds_all[4][256];
  float* wlds = wlds_all[wid];

  int s0 = n;
  float4 e0 = make_float4(-1e30f, -1e30f, -1e30f, -1e30f);
  if (lane < tot) {
    if (lane < deg) s0 = esrc[beg + lane];
    float4 av = as4[s0];
    e0.x = leaky(av.x + adv.x); e0.y = leaky(av.y + adv.y);
    e0.z = leaky(av.z + adv.z); e0.w = leaky(av.w + adv.w);
  }
  float4 mx = e0;
  for (int i = lane + 64; i < tot; i += 64) {
    int s = (i < deg) ? esrc[beg + i] : n;
    float4 av = as4[s];
    mx.x = fmaxf(mx.x, leaky(av.x + adv.x));
    mx.y = fmaxf(mx.y, leaky(av.y + adv.y));
    mx.z = fmaxf(mx.z, leaky(av.z + adv.z));
    mx.w = fmaxf(mx.w, leaky(av.w + adv.w));
  }
#pragma unroll
  for (int off = 32; off >= 1; off >>= 1) {
    mx.x = fmaxf(mx.x, __shfl_xor(mx.x, off, 64));
    mx.y = fmaxf(mx.y, __shfl_xor(mx.y, off, 64));
    mx.z = fmaxf(mx.z, __shfl_xor(mx.z, off, 64));
    mx.w = fmaxf(mx.w, __shfl_xor(mx.w, off, 64));
  }
  float4 sm;
  sm.x = __expf(e0.x - mx.x); sm.y = __expf(e0.y - mx.y);
  sm.z = __expf(e0.z - mx.z); sm.w = __expf(e0.w - mx.w);
  for (int i = lane + 64; i < tot; i += 64) {
    int s = (i < deg) ? esrc[beg + i] : n;
    float4 av = as4[s];
    sm.x += __expf(leaky(av.x + adv.x) - mx.x);
    sm.y += __expf(leaky(av.y + adv.y) - mx.y);
    sm.z += __expf(leaky(av.z + adv.z) - mx.z);
    sm.w += __expf(leaky(av.w + adv.w) - mx.w);
  }
#pragma unroll
  for (int off = 32; off >= 1; off >>= 1) {
    sm.x += __shfl_xor(sm.x, off, 64);
    sm.y += __shfl_xor(sm.y, off, 64);
    sm.z += __shfl_xor(sm.z, off, 64);
    sm.w += __shfl_xor(sm.w, off, 64);
  }
  float4 inv;
  inv.x = 1.f / (sm.x + 1e-16f); inv.y = 1.f / (sm.y + 1e-16f);
  inv.z = 1.f / (sm.z + 1e-16f); inv.w = 1.f / (sm.w + 1e-16f);

  float4 acc0 = make_float4(0.f, 0.f, 0.f, 0.f);
  float4 acc1 = make_float4(0.f, 0.f, 0.f, 0.f);
  const char* hb = (const char*)h1p + (size_t)lane * 16;

  for (int base = 0; base < tot; base += 64) {
    int sl;
    float4 wl;
    if (base == 0) {
      sl = s0;
      wl.x = __expf(e0.x - mx.x) * inv.x;
      wl.y = __expf(e0.y - mx.y) * inv.y;
      wl.z = __expf(e0.z - mx.z) * inv.z;
      wl.w = __expf(e0.w - mx.w) * inv.w;
    } else {
      int i = base + lane;
      sl = n;
      wl = make_float4(0.f, 0.f, 0.f, 0.f);
      if (i < tot) {
        if (i < deg) sl = esrc[beg + i];
        float4 av = as4[sl];
        wl.x = __expf(leaky(av.x + adv.x) - mx.x) * inv.x;
        wl.y = __expf(leaky(av.y + adv.y) - mx.y) * inv.y;
        wl.z = __expf(leaky(av.z + adv.z) - mx.z) * inv.z;
        wl.w = __expf(leaky(av.w + adv.w) - mx.w) * inv.w;
      }
    }
    *(float4*)&wlds[lane * 4] = wl;   // intra-wave LDS, no barrier needed
    int m = min(64, tot - base);
    int j = 0;
    for (; j + 2 <= m; j += 2) {
      int sA = __builtin_amdgcn_readlane(sl, j);
      int sB = __builtin_amdgcn_readlane(sl, j + 1);
      float wA = wlds[j * 4 + head];
      float wB = wlds[(j + 1) * 4 + head];
      uint4 hA = *(const uint4*)(hb + (size_t)sA * 1024);
      uint4 hB = *(const uint4*)(hb + (size_t)sB * 1024);
      acc0.x = fmaf(wA, bflo(hA.x), acc0.x);
      acc0.y = fmaf(wA, bfhi(hA.x), acc0.y);
      acc0.z = fmaf(wA, bflo(hA.y), acc0.z);
      acc0.w = fmaf(wA, bfhi(hA.y), acc0.w);
      acc1.x = fmaf(wA, bflo(hA.z), acc1.x);
      acc1.y = fmaf(wA, bfhi(hA.z), acc1.y);
      acc1.z = fmaf(wA, bflo(hA.w), acc1.z);
      acc1.w = fmaf(wA, bfhi(hA.w), acc1.w);
      acc0.x = fmaf(wB, bflo(hB.x), acc0.x);
      acc0.y = fmaf(wB, bfhi(hB.x), acc0.y);
      acc0.z = fmaf(wB, bflo(hB.y), acc0.z);
      acc0.w = fmaf(wB, bfhi(hB.y), acc0.w);
      acc1.x = fmaf(wB, bflo(hB.z), acc1.x);
      acc1.y = fmaf(wB, bfhi(hB.z), acc1.y);
      acc1.z = fmaf(wB, bflo(hB.w), acc1.z);
      acc1.w = fmaf(wB, bfhi(hB.w), acc1.w);
    }
    if (j < m) {
      int sA = __builtin_amdgcn_readlane(sl, j);
      float wA = wlds[j * 4 + head];
      uint4 hA = *(const uint4*)(hb + (size_t)sA * 1024);
      acc0.x = fmaf(wA, bflo(hA.x), acc0.x);
      acc0.y = fmaf(wA, bfhi(hA.x), acc0.y);
      acc0.z = fmaf(wA, bflo(hA.y), acc0.z);
      acc0.w = fmaf(wA, bfhi(hA.y), acc0.w);
      acc1.x = fmaf(wA, bflo(hA.z), acc1.x);
      acc1.y = fmaf(wA, bfhi(hA.z), acc1.y);
      acc1.z = fmaf(wA, bflo(hA.w), acc1.z);
      acc1.w = fmaf(wA, bfhi(hA.w), acc1.w);
    }
  }
  const float4* b4 = (const float4*)b1;
  float4 ba = b4[2 * lane], bb = b4[2 * lane + 1];
  float4 r0, r1;
  r0.x = fmaxf(acc0.x + ba.x, 0.f); r0.y = fmaxf(acc0.y + ba.y, 0.f);
  r0.z = fmaxf(acc0.z + ba.z, 0.f); r0.w = fmaxf(acc0.w + ba.w, 0.f);
  r1.x = fmaxf(acc1.x + bb.x, 0.f); r1.y = fmaxf(acc1.y + bb.y, 0.f);
  r1.z = fmaxf(acc1.z + bb.z, 0.f); r1.w = fmaxf(acc1.w + bb.w, 0.f);
  uint4 o;
  o.x = f2bf(r0.x) | (f2bf(r0.y) << 16);
  o.y = f2bf(r0.z) | (f2bf(r0.w) << 16);
  o.z = f2bf(r1.x) | (f2bf(r1.y) << 16);
  o.w = f2bf(r1.z) | (f2bf(r1.w) << 16);
  o1b[(size_t)n * 64 + lane] = o;
}

// ---------------- layer-2 softmax + aggregation: 1 wave per node ----------------
__global__ __launch_bounds__(256) void agg2_k(const int* __restrict__ rowstart,
                                              const int* __restrict__ esrc,
                                              const float* __restrict__ as,
                                              const float* __restrict__ ad,
                                              const ushort* __restrict__ h2p,
                                              const float* __restrict__ b2,
                                              float* __restrict__ out2) {
  const int lane = threadIdx.x & 63;
  const int wid = threadIdx.x >> 6;
  const int n = blockIdx.x * 4 + wid;
  const int beg = rowstart[n];
  const int deg = rowstart[n + 1] - beg;
  const int tot = deg + 1;
  const float adv = ad[n];

  __shared__ float wlds_all[4][64];
  float* wlds = wlds_all[wid];

  int s0 = n;
  float e0 = -1e30f;
  if (lane < tot) {
    if (lane < deg) s0 = esrc[beg + lane];
    e0 = leaky(as[s0] + adv);
  }
  float mx = e0;
  for (int i = lane + 64; i < tot; i += 64) {
    int s = (i < deg) ? esrc[beg + i] : n;
    mx = fmaxf(mx, leaky(as[s] + adv));
  }
#pragma unroll
  for (int off = 32; off >= 1; off >>= 1) mx = fmaxf(mx, __shfl_xor(mx, off, 64));
  float sm = __expf(e0 - mx);
  for (int i = lane + 64; i < tot; i += 64) {
    int s = (i < deg) ? esrc[beg + i] : n;
    sm += __expf(leaky(as[s] + adv) - mx);
  }
#pragma unroll
  for (int off = 32; off >= 1; off >>= 1) sm += __shfl_xor(sm, off, 64);
  float inv = 1.f / (sm + 1e-16f);

  float2 acc = make_float2(0.f, 0.f);
  const char* hb = (const char*)h2p + (size_t)lane * 4;
  for (int base = 0; base < tot; base += 64) {
    int sl;
    float wl;
    if (base == 0) {
      sl = s0;
      wl = __expf(e0 - mx) * inv;
    } else {
      int i = base + lane;
      sl = n; wl = 0.f;
      if (i < tot) {
        if (i < deg) sl = esrc[beg + i];
        wl = __expf(leaky(as[sl] + adv) - mx) * inv;
      }
    }
    wlds[lane] = wl;
    int m = min(64, tot - base);
    int j = 0;
    for (; j + 2 <= m; j += 2) {
      int sA = __builtin_amdgcn_readlane(sl, j);
      int sB = __builtin_amdgcn_readlane(sl, j + 1);
      float wA = wlds[j];
      float wB = wlds[j + 1];
      unsigned hA = *(const unsigned*)(hb + (size_t)sA * 256);
      unsigned hB = *(const unsigned*)(hb + (size_t)sB * 256);
      acc.x = fmaf(wA, bflo(hA), acc.x);
      acc.y = fmaf(wA, bfhi(hA), acc.y);
      acc.x = fmaf(wB, bflo(hB), acc.x);
      acc.y = fmaf(wB, bfhi(hB), acc.y);
    }
    if (j < m) {
      int sA = __builtin_amdgcn_readlane(sl, j);
      float wA = wlds[j];
      unsigned hA = *(const unsigned*)(hb + (size_t)sA * 256);
      acc.x = fmaf(wA, bflo(hA), acc.x);
      acc.y = fmaf(wA, bfhi(hA), acc.y);
    }
  }
  float2 bb = ((const float2*)b2)[lane];
  float2 r;
  r.x = fmaxf(acc.x + bb.x, 0.f);
  r.y = fmaxf(acc.y + bb.y, 0.f);
  ((float2*)(out2 + (size_t)n * 128))[lane] = r;
}

// ---------------- pooling + FC (one block per graph, no atomics) ----------------
__global__ __launch_bounds__(128) void poolfc_k(const int* __restrict__ gstart,
                                                const float* __restrict__ out2,
                                                const float* __restrict__ fcw,
                                                const float* __restrict__ fcb,
                                                float* __restrict__ out) {
  const int g = blockIdx.x;
  const int tid = threadIdx.x;
  const int beg = gstart[g], end = gstart[g + 1];
  const int cnt = end - beg;
  float acc = 0.f;
  int n = beg;
  for (; n + 4 <= end; n += 4) {
    float v0 = out2[(size_t)(n + 0) * 128 + tid];
    float v1 = out2[(size_t)(n + 1) * 128 + tid];
    float v2 = out2[(size_t)(n + 2) * 128 + tid];
    float v3 = out2[(size_t)(n + 3) * 128 + tid];
    acc += (v0 + v1) + (v2 + v3);
  }
  for (; n < end; n++) acc += out2[(size_t)n * 128 + tid];
  __shared__ float pg[128];
  pg[tid] = acc / (float)(cnt > 0 ? cnt : 1);
  __syncthreads();
  if (tid < 64) {
    float o = fcb[tid];
#pragma unroll 8
    for (int c = 0; c < 128; c++) o = fmaf(pg[c], fcw[c * 64 + tid], o);
    out[g * 64 + tid] = o;
  }
}

// ---------------- launch ----------------
extern "C" void kernel_launch(void* const* d_in, const int* in_sizes, int n_in,
                              void* d_out, int out_size, void* d_ws, size_t ws_size,
                              hipStream_t stream) {
  const float* x   = (const float*)d_in[0];
  const int*   ei  = (const int*)d_in[1];
  const int*   bat = (const int*)d_in[2];
  const float* W1  = (const float*)d_in[3];
  const float* a1s = (const float*)d_in[4];
  const float* a1d = (const float*)d_in[5];
  const float* b1  = (const float*)d_in[6];
  const float* W2  = (const float*)d_in[7];
  const float* a2s = (const float*)d_in[8];
  const float* a2d = (const float*)d_in[9];
  const float* b2  = (const float*)d_in[10];
  const float* fcw = (const float*)d_in[11];
  const float* fcb = (const float*)d_in[12];
  float* out = (float*)d_out;

  char* ws = (char*)d_ws;
  size_t off = 0;
  auto alloc = [&](size_t bytes) -> void* {
    void* p = ws + off;
    off = (off + bytes + 255) & ~(size_t)255;
    return p;
  };

  int*   count    = (int*)alloc((size_t)NN * 4);
  int*   rowstart = (int*)alloc((size_t)(NN + 1) * 4);
  int*   cursor   = (int*)alloc((size_t)NN * 4);
  int*   esrc     = (int*)alloc((size_t)EE * 4);
  int*   gstart   = (int*)alloc((size_t)(GG + 1) * 4);
  ushort* xb      = (ushort*)alloc((size_t)NPAD * 256 * 2);
  ushort* w1hi    = (ushort*)alloc((size_t)512 * 256 * 2);
  ushort* w1lo    = (ushort*)alloc((size_t)512 * 256 * 2);
  ushort* w2hi    = (ushort*)alloc((size_t)128 * 512 * 2);
  ushort* w2lo    = (ushort*)alloc((size_t)128 * 512 * 2);
  ushort* h1p     = (ushort*)alloc((size_t)NPAD * 512 * 2);
  ushort* o1b     = (ushort*)alloc((size_t)NPAD * 512 * 2);
  ushort* h2p     = (ushort*)alloc((size_t)NPAD * 128 * 2);
  float* as1      = (float*)alloc((size_t)NN * 4 * 4);
  float* ad1      = (float*)alloc((size_t)NN * 4 * 4);
  float* as2      = (float*)alloc((size_t)NN * 4);
  float* ad2      = (float*)alloc((size_t)NN * 4);
  float* out2     = (float*)alloc((size_t)NN * 128 * 4);
  (void)ws_size; (void)in_sizes; (void)n_in; (void)out_size;

  hipMemsetAsync(count, 0, (size_t)NN * 4, stream);
  hist_k<<<(EE + 255) / 256, 256, 0, stream>>>(ei, count);
  scan_k<<<1, 1024, 0, stream>>>(count, rowstart, cursor);
  fill_k<<<(EE + 255) / 256, 256, 0, stream>>>(ei, cursor, esrc);
  gstart_k<<<(NN + 255) / 256, 256, 0, stream>>>(bat, gstart);

  packall_k<<<(PX_ITEMS + PW1 + PW2 + 255) / 256, 256, 0, stream>>>(
      x, W1, W2, (uint4*)xb, w1hi, w1lo, w2hi, w2lo);

  gemmt_k<<<dim3(512 / 64, NT), 256, 0, stream>>>(xb, w1hi, w1lo, (unsigned*)h1p, 256, 512);
  alpha1b_k<<<NN / 4, 256, 0, stream>>>((const uint4*)h1p, a1s, a1d, as1, ad1);
  agg1_k<<<NN / 4, 256, 0, stream>>>(rowstart, esrc, as1, ad1, h1p, b1, (uint4*)o1b);

  gemmt_k<<<dim3(128 / 64, NT), 256, 0, stream>>>(o1b, w2hi, w2lo, (unsigned*)h2p, 512, 128);
  alpha2b_k<<<NN / 4, 256, 0, stream>>>((const unsigned*)h2p, a2s, a2d, as2, ad2);
  agg2_k<<<NN / 4, 256, 0, stream>>>(rowstart, esrc, as2, ad2, h2p, b2, out2);

  poolfc_k<<<GG, 128, 0, stream>>>(gstart, out2, fcw, fcb, out);
}